// Round 14
// baseline (1051.448 us; speedup 1.0000x reference)
//
#include <hip/hip_runtime.h>
#include <math.h>

#ifndef M_PI
#define M_PI 3.14159265358979323846
#endif

#define NGRID 513
#define NCELL 512
#define NINT  511
#define NB    4

constexpr int N2G = NGRID * NGRID;   // 263169
constexpr int NI2 = NINT * NINT;     // 261121
constexpr int NTT = NGRID * NINT;    // 262143

typedef unsigned short ushort;
typedef __attribute__((ext_vector_type(8))) short short8;
typedef __attribute__((ext_vector_type(8))) unsigned short ushort8;
typedef __attribute__((ext_vector_type(4))) float f32x4;

// ---------------------------------------------------------------------------
// bf16 split helpers (RNE)
// ---------------------------------------------------------------------------
__device__ __forceinline__ ushort f2bf(float x) {
    unsigned u = __float_as_uint(x);
    unsigned r = u + 0x7FFFu + ((u >> 16) & 1u);
    return (ushort)(r >> 16);
}
__device__ __forceinline__ float bf2f(ushort h) {
    return __uint_as_float(((unsigned)h) << 16);
}

// ---------------------------------------------------------------------------
// FEM Darcy operator at interior node (i,j), i,j in 1..511
// ---------------------------------------------------------------------------
__device__ __forceinline__ float darcyA(const float* __restrict__ x,
                                        const float* __restrict__ a,
                                        int i, int j) {
    const float c23 = 2.0f / 3.0f, c16 = 1.0f / 6.0f, c13 = 1.0f / 3.0f;
    float a00 = a[(i - 1) * NCELL + (j - 1)];
    float a01 = a[(i - 1) * NCELL + j];
    float a10 = a[i * NCELL + (j - 1)];
    float a11 = a[i * NCELL + j];
    const float* xm = x + (i - 1) * NGRID;
    const float* xc = x + i * NGRID;
    const float* xp = x + (i + 1) * NGRID;
    return c23 * (a00 + a01 + a10 + a11) * xc[j]
         - c16 * ((a00 + a01) * xm[j] + (a10 + a11) * xp[j]
                + (a00 + a10) * xc[j - 1] + (a01 + a11) * xc[j + 1])
         - c13 * (a00 * xm[j - 1] + a01 * xm[j + 1]
                + a10 * xp[j - 1] + a11 * xp[j + 1]);
}

__global__ void k_stencil(const float* __restrict__ xin,
                          const float* __restrict__ a,
                          const float* __restrict__ f,
                          const float* __restrict__ dinv,
                          float* __restrict__ out, int mode) {
    int b = blockIdx.z;
    int j = blockIdx.x * 16 + threadIdx.x;
    int i = blockIdx.y * 16 + threadIdx.y;
    if (i >= NGRID || j >= NGRID) return;
    const float* xb = xin + (long long)b * N2G;
    const float* ab = a + (long long)b * NCELL * NCELL;
    long long idx = (long long)b * N2G + (long long)i * NGRID + j;
    bool interior = (i >= 1 && i <= NINT && j >= 1 && j <= NINT);
    if (!interior) {
        out[idx] = (mode == 0) ? f[idx] : 0.0f;
        return;
    }
    float Ax = darcyA(xb, ab, i, j);
    if (mode == 0) {
        out[idx] = f[idx] - Ax;
    } else {
        out[idx] = Ax;
    }
}

// ---------------------------------------------------------------------------
// Paired weighted-Jacobi: 2 sweeps per launch via LDS staging (halo 2).
// Bit-identical arithmetic to two k_stencil mode-1 passes.
// ---------------------------------------------------------------------------
__global__ void k_jacobi2(const float* __restrict__ xin,
                          const float* __restrict__ a,
                          const float* __restrict__ f,
                          const float* __restrict__ dinv,
                          float* __restrict__ out) {
    __shared__ float sx[20][20];
    __shared__ float sa[19][20];
    __shared__ float sf[18][18];
    __shared__ float sd[18][18];
    __shared__ float s1[18][20];
    const float c23 = 2.0f / 3.0f, c16 = 1.0f / 6.0f, c13 = 1.0f / 3.0f;
    int b = blockIdx.z;
    const float* xb = xin + (long long)b * N2G;
    const float* ab = a + (long long)b * NCELL * NCELL;
    const float* fb = f + (long long)b * N2G;
    const float* db = dinv + (long long)b * NI2;
    int ox = blockIdx.x * 16, oy = blockIdx.y * 16;
    int tx = threadIdx.x, ty = threadIdx.y;
    int tid = ty * 16 + tx;

    for (int idx = tid; idx < 400; idx += 256) {
        int ly = idx / 20, lx = idx % 20;
        int gy = oy - 2 + ly, gx = ox - 2 + lx;
        bool in = (gy >= 0 && gy < NGRID && gx >= 0 && gx < NGRID);
        sx[ly][lx] = in ? xb[(long long)gy * NGRID + gx] : 0.0f;
    }
    for (int idx = tid; idx < 361; idx += 256) {
        int ly = idx / 19, lx = idx % 19;
        int gy = oy - 2 + ly, gx = ox - 2 + lx;
        bool in = (gy >= 0 && gy < NCELL && gx >= 0 && gx < NCELL);
        sa[ly][lx] = in ? ab[(long long)gy * NCELL + gx] : 0.0f;
    }
    for (int idx = tid; idx < 324; idx += 256) {
        int ly = idx / 18, lx = idx % 18;
        int gy = oy - 1 + ly, gx = ox - 1 + lx;
        bool ing = (gy >= 0 && gy < NGRID && gx >= 0 && gx < NGRID);
        bool itr = (gy >= 1 && gy <= NINT && gx >= 1 && gx <= NINT);
        sf[ly][lx] = ing ? fb[(long long)gy * NGRID + gx] : 0.0f;
        sd[ly][lx] = itr ? db[(long long)(gy - 1) * NINT + (gx - 1)] : 0.0f;
    }
    __syncthreads();

    for (int idx = tid; idx < 324; idx += 256) {
        int ly = idx / 18, lx = idx % 18;
        int gy = oy - 1 + ly, gx = ox - 1 + lx;
        float v = 0.0f;
        if (gy >= 0 && gy < NGRID && gx >= 0 && gx < NGRID) {
            float xc = sx[ly + 1][lx + 1];
            if (gy >= 1 && gy <= NINT && gx >= 1 && gx <= NINT) {
                float a00 = sa[ly][lx], a01 = sa[ly][lx + 1];
                float a10 = sa[ly + 1][lx], a11 = sa[ly + 1][lx + 1];
                float Ax = c23 * (a00 + a01 + a10 + a11) * xc
                    - c16 * ((a00 + a01) * sx[ly][lx + 1] + (a10 + a11) * sx[ly + 2][lx + 1]
                           + (a00 + a10) * sx[ly + 1][lx] + (a01 + a11) * sx[ly + 1][lx + 2])
                    - c13 * (a00 * sx[ly][lx] + a01 * sx[ly][lx + 2]
                           + a10 * sx[ly + 2][lx] + a11 * sx[ly + 2][lx + 2]);
                v = xc + 0.75f * sd[ly][lx] * (sf[ly][lx] - Ax);
            } else {
                v = xc;
            }
        }
        s1[ly][lx] = v;
    }
    __syncthreads();

    int gy = oy + ty, gx = ox + tx;
    if (gy < NGRID && gx < NGRID) {
        float v;
        float xc = s1[ty + 1][tx + 1];
        if (gy >= 1 && gy <= NINT && gx >= 1 && gx <= NINT) {
            float a00 = sa[ty + 1][tx + 1], a01 = sa[ty + 1][tx + 2];
            float a10 = sa[ty + 2][tx + 1], a11 = sa[ty + 2][tx + 2];
            float Ax = c23 * (a00 + a01 + a10 + a11) * xc
                - c16 * ((a00 + a01) * s1[ty][tx + 1] + (a10 + a11) * s1[ty + 2][tx + 1]
                       + (a00 + a10) * s1[ty + 1][tx] + (a01 + a11) * s1[ty + 1][tx + 2])
                - c13 * (a00 * s1[ty][tx] + a01 * s1[ty][tx + 2]
                       + a10 * s1[ty + 2][tx] + a11 * s1[ty + 2][tx + 2]);
            v = xc + 0.75f * sd[ty + 1][tx + 1] * (sf[ty + 1][tx + 1] - Ax);
        } else {
            v = xc;
        }
        out[(long long)b * N2G + (long long)gy * NGRID + gx] = v;
    }
}

__global__ void k_dinv(const float* __restrict__ a, float* __restrict__ dinv) {
    long long idx = (long long)blockIdx.x * blockDim.x + threadIdx.x;
    if (idx >= (long long)NB * NI2) return;
    int b = (int)(idx / NI2);
    int rem = (int)(idx % NI2);
    int p = rem / NINT, q = rem % NINT;
    const float* ab = a + (long long)b * NCELL * NCELL;
    float s = ab[p * NCELL + q] + ab[p * NCELL + q + 1]
            + ab[(p + 1) * NCELL + q] + ab[(p + 1) * NCELL + q + 1];
    dinv[idx] = 1.0f / ((2.0f / 3.0f) * s);
}

// ---------------------------------------------------------------------------
// Static bf16 matrix generation (hi/lo planes, K-padded, integer arg reduce)
// ---------------------------------------------------------------------------
__device__ __forceinline__ void wsplit(double v, ushort* Dh, ushort* Dl, int idx) {
    float vf = (float)v;
    ushort h = f2bf(vf);
    Dh[idx] = h;
    Dl[idx] = f2bf(vf - bf2f(h));
}

__global__ void k_genDSTA(ushort* __restrict__ Dh, ushort* __restrict__ Dl) {
    int idx = blockIdx.x * 256 + threadIdx.x;
    if (idx >= 513 * 512) return;
    int u = idx / 512, k = idx % 512;
    double v = 0.0;
    if (k < 511) {
        int t = ((u - 256) * (k + 1)) % 1024;
        if (t < 0) t += 1024;
        v = sin((M_PI / 512.0) * (double)t);
    }
    wsplit(v, Dh, Dl, idx);
}

__global__ void k_genDSTB(ushort* __restrict__ Dh, ushort* __restrict__ Dl) {
    int idx = blockIdx.x * 256 + threadIdx.x;
    if (idx >= 513 * 512) return;
    int v = idx / 512, k = idx % 512;
    double val = 0.0;
    if (k < 511) {
        int t = ((v - 256) * (k + 1)) % 1024;
        if (t < 0) t += 1024;
        val = sin((M_PI / 512.0) * (double)t) * (-1.0 / 262144.0);
    }
    wsplit(val, Dh, Dl, idx);
}

__global__ void k_genFA(ushort* __restrict__ Dh, ushort* __restrict__ Dl) {
    int idx = blockIdx.x * 256 + threadIdx.x;
    if (idx >= 511 * 1056) return;
    int y = idx / 1056, k = idx % 1056;
    double v = 0.0;
    if (k < 1026) {
        int m = (k < 513) ? k : (k - 513);
        long t = ((long)y * (m - 255)) % 1025;
        if (t < 0) t += 1025;
        double ang = (2.0 * M_PI / 1025.0) * (double)t;
        v = (k < 513) ? cos(ang) : -sin(ang);
    }
    wsplit(v, Dh, Dl, idx);
}

__global__ void k_genFB(ushort* __restrict__ Dh, ushort* __restrict__ Dl) {
    int idx = blockIdx.x * 256 + threadIdx.x;
    if (idx >= 1022 * 1056) return;
    int n = idx / 1056, k = idx % 1056;
    double v = 0.0;
    if (k < 1026) {
        int m = (k < 513) ? k : (k - 513);
        int y = (n < 511) ? n : (n - 511);
        long t = ((long)y * (m - 255)) % 1025;
        if (t < 0) t += 1025;
        double ang = (2.0 * M_PI / 1025.0) * (double)t;
        bool ktop = (k < 513), nleft = (n < 511);
        if (ktop && nleft)        v = cos(ang);
        else if (ktop && !nleft)  v = -sin(ang);
        else if (!ktop && nleft)  v = sin(ang);
        else                      v = cos(ang);
    }
    wsplit(v, Dh, Dl, idx);
}

// ---------------------------------------------------------------------------
// Dynamic fp32 -> bf16 hi/lo conversion (inputs to gemm1 / gemm3).
// ---------------------------------------------------------------------------
__global__ void k_cvtA(const float* __restrict__ s1, const float* __restrict__ s2,
                       long long bs1, long long bs2, int ld1, int ld2, int S,
                       int M, int K, int Kp,
                       ushort* __restrict__ Dh, ushort* __restrict__ Dl) {
    int b = blockIdx.y;
    int idx = blockIdx.x * 256 + threadIdx.x;
    if (idx >= M * Kp) return;
    int m = idx / Kp, k = idx % Kp;
    float v = 0.0f;
    if (k < K)
        v = (k < S) ? s1[b * bs1 + (long long)m * ld1 + k]
                    : s2[b * bs2 + (long long)m * ld2 + (k - S)];
    long long o = (long long)b * M * Kp + idx;
    ushort h = f2bf(v);
    Dh[o] = h;
    Dl[o] = f2bf(v - bf2f(h));
}

__global__ void k_cvtBt(const float* __restrict__ s1,
                        long long bs1, int ld1,
                        int N, int K, int Kp,
                        ushort* __restrict__ Dh, ushort* __restrict__ Dl) {
    int b = blockIdx.y;
    int idx = blockIdx.x * 256 + threadIdx.x;
    if (idx >= N * Kp) return;
    int n = idx / Kp, k = idx % Kp;
    float v = 0.0f;
    if (k < K)
        v = s1[b * bs1 + (long long)k * ld1 + n];
    long long o = (long long)b * N * Kp + idx;
    ushort h = f2bf(v);
    Dh[o] = h;
    Dl[o] = f2bf(v - bf2f(h));
}

// ---------------------------------------------------------------------------
// Fused split-K reduce + bf16 convert (GEMM->GEMM handoffs).
// ---------------------------------------------------------------------------
__global__ void k_redA(const float* __restrict__ P, int nsplit,
                       ushort* __restrict__ Dh, ushort* __restrict__ Dl) {
    int b = blockIdx.y;
    int idx = blockIdx.x * 256 + threadIdx.x;
    if (idx >= 513 * 512) return;
    int m = idx / 512, k = idx % 512;
    float v = 0.0f;
    if (k < 511) {
        long long base = (long long)m * 511 + k;
        #pragma unroll 4
        for (int s = 0; s < nsplit; ++s)
            v += P[((long long)b * nsplit + s) * NTT + base];
    }
    long long o = (long long)b * 513 * 512 + idx;
    ushort h = f2bf(v);
    Dh[o] = h;
    Dl[o] = f2bf(v - bf2f(h));
}

__global__ void k_redBt(const float* __restrict__ P, int nsplit,
                        ushort* __restrict__ Dh, ushort* __restrict__ Dl) {
    int b = blockIdx.y;
    int idx = blockIdx.x * 256 + threadIdx.x;
    if (idx >= 511 * 1056) return;
    int n = idx / 1056, k = idx % 1056;
    float v = 0.0f;
    if (k < 1026) {
        int row = (k < 513) ? n : (511 + n);
        int col = (k < 513) ? k : (k - 513);
        long long base = (long long)row * 513 + col;
        float acc = 0.0f;
        #pragma unroll 4
        for (int s = 0; s < nsplit; ++s)
            acc += P[((long long)b * nsplit + s) * (1022LL * 513) + base];
        v = (k < 513) ? acc : -acc;
    }
    long long o = (long long)b * 511 * 1056 + idx;
    ushort h = f2bf(v);
    Dh[o] = h;
    Dl[o] = f2bf(v - bf2f(h));
}

// ---------------------------------------------------------------------------
// MFMA real GEMM, 3-term split-bf16 (hh + hl + lh), 16x16x32 bf16 MFMA.
// (unchanged from R8 — validated)
// ---------------------------------------------------------------------------
__global__ __launch_bounds__(256) void k_mgemm(
    const ushort* __restrict__ Ah, const ushort* __restrict__ Al, long long bsA,
    const ushort* __restrict__ Bh, const ushort* __restrict__ Bl, long long bsB,
    float* __restrict__ C, long long bsC,
    int M, int N, int Kp, int nsplit) {
    __shared__ ushort sAh[128 * 40];
    __shared__ ushort sAl[128 * 40];
    __shared__ ushort sBh[128 * 40];
    __shared__ ushort sBl[128 * 40];

    int bz = blockIdx.z, b = bz / nsplit, ks = bz % nsplit;
    int kchunk = (((Kp + nsplit - 1) / nsplit) + 31) & ~31;
    int kbeg = ks * kchunk;
    int kend = min(Kp, kbeg + kchunk);

    Ah += b * bsA; Al += b * bsA;
    Bh += b * bsB; Bl += b * bsB;
    C += ((long long)b * nsplit + ks) * bsC;

    int bm = blockIdx.y * 128, bn = blockIdx.x * 128;
    int tid = threadIdx.x;
    int wave = tid >> 6, lane = tid & 63;
    int wm = (wave >> 1) * 64, wn = (wave & 1) * 64;
    int quad = lane >> 4, l16 = lane & 15;

    f32x4 zf = {0.f, 0.f, 0.f, 0.f};
    f32x4 acc[4][4];
    #pragma unroll
    for (int i = 0; i < 4; ++i)
        #pragma unroll
        for (int j = 0; j < 4; ++j) acc[i][j] = zf;

    int srow = tid >> 2;
    int sk8 = (tid & 3) * 8;

    for (int kt = kbeg; kt < kend; kt += 32) {
        #pragma unroll
        for (int h = 0; h < 2; ++h) {
            int row = srow + 64 * h;
            ushort8 vh = {0, 0, 0, 0, 0, 0, 0, 0};
            ushort8 vl = {0, 0, 0, 0, 0, 0, 0, 0};
            int gm = bm + row;
            if (gm < M) {
                vh = *(const ushort8*)(Ah + (long long)gm * Kp + kt + sk8);
                vl = *(const ushort8*)(Al + (long long)gm * Kp + kt + sk8);
            }
            *(ushort8*)(sAh + row * 40 + sk8) = vh;
            *(ushort8*)(sAl + row * 40 + sk8) = vl;
            ushort8 wh = {0, 0, 0, 0, 0, 0, 0, 0};
            ushort8 wl = {0, 0, 0, 0, 0, 0, 0, 0};
            int gn = bn + row;
            if (gn < N) {
                wh = *(const ushort8*)(Bh + (long long)gn * Kp + kt + sk8);
                wl = *(const ushort8*)(Bl + (long long)gn * Kp + kt + sk8);
            }
            *(ushort8*)(sBh + row * 40 + sk8) = wh;
            *(ushort8*)(sBl + row * 40 + sk8) = wl;
        }
        __syncthreads();

        short8 afh[4], afl[4], bfh[4], bfl[4];
        #pragma unroll
        for (int t = 0; t < 4; ++t) {
            int ar = wm + t * 16 + l16;
            afh[t] = *(const short8*)(sAh + ar * 40 + quad * 8);
            afl[t] = *(const short8*)(sAl + ar * 40 + quad * 8);
            int br = wn + t * 16 + l16;
            bfh[t] = *(const short8*)(sBh + br * 40 + quad * 8);
            bfl[t] = *(const short8*)(sBl + br * 40 + quad * 8);
        }
        #pragma unroll
        for (int mt = 0; mt < 4; ++mt)
            #pragma unroll
            for (int nt = 0; nt < 4; ++nt) {
                acc[mt][nt] = __builtin_amdgcn_mfma_f32_16x16x32_bf16(
                    afh[mt], bfh[nt], acc[mt][nt], 0, 0, 0);
                acc[mt][nt] = __builtin_amdgcn_mfma_f32_16x16x32_bf16(
                    afh[mt], bfl[nt], acc[mt][nt], 0, 0, 0);
                acc[mt][nt] = __builtin_amdgcn_mfma_f32_16x16x32_bf16(
                    afl[mt], bfh[nt], acc[mt][nt], 0, 0, 0);
            }
        __syncthreads();
    }

    #pragma unroll
    for (int mt = 0; mt < 4; ++mt) {
        #pragma unroll
        for (int r = 0; r < 4; ++r) {
            int gm = bm + wm + mt * 16 + quad * 4 + r;
            if (gm >= M) continue;
            long long rowoff = (long long)gm * N;
            #pragma unroll
            for (int nt = 0; nt < 4; ++nt) {
                int gn = bn + wn + nt * 16 + l16;
                if (gn < N) C[rowoff + gn] = acc[mt][nt][r];
            }
        }
    }
}

// ---------------------------------------------------------------------------
// Sum nsplit dense [M x N] partials -> strided fp32 output (row stride ldo).
// ---------------------------------------------------------------------------
__global__ void k_reduce(const float* __restrict__ Pr,
                         float* __restrict__ outR,
                         int MN, int N, int ldo, long long bsOut, int nsplit) {
    int b = blockIdx.y;
    for (int idx = blockIdx.x * 256 + threadIdx.x; idx < MN;
         idx += gridDim.x * 256) {
        float sr = 0.0f;
        #pragma unroll 4
        for (int s = 0; s < nsplit; ++s)
            sr += Pr[((long long)b * nsplit + s) * MN + idx];
        int m = idx / N, n = idx - m * N;
        outR[(long long)b * bsOut + (long long)m * ldo + n] = sr;
    }
}

// ---------------------------------------------------------------------------
// Complex multi-channel 3x3 conv (R14 = R13 + scalarized weights):
// weights are read from GLOBAL with wave-uniform indices -> compiler emits
// s_load into SGPRs (no LDS instructions for weights; SGPR operand on the
// FMA is free). Cuts wave LDS instr per (ci,p,q) from 6 b64 to 2 b64 —
// the R13 limiter (LDS port 3x oversubscribed vs FMA issue).
// Tile config unchanged from R10/R13 (2 px/thread, 21 KB LDS, VGPR 40).
// ---------------------------------------------------------------------------
template <int CIN, int COUT, bool INC>
__global__ __launch_bounds__(256) void k_mcc(
    const float* __restrict__ xr, const float* __restrict__ xi,
    const float* __restrict__ wr, const float* __restrict__ wi,
    float* __restrict__ yr, float* __restrict__ yi,
    int wb, int ws1, int ws2, int conjt) {
    __shared__ float2 tile[CIN][34][18];
    int b = blockIdx.z;
    int tid = threadIdx.y * 16 + threadIdx.x;

    int ox = blockIdx.x * 16, oy = blockIdx.y * 32;
    for (int idx = tid; idx < CIN * 34 * 18; idx += 256) {
        int ci = idx / (34 * 18), r2 = idx % (34 * 18);
        int ly = r2 / 18, lx = r2 % 18;
        int gy = oy + ly - 1, gx = ox + lx - 1;
        bool in = (gy >= 0 && gy < NGRID && gx >= 0 && gx < NGRID);
        long long gi = (long long)(b * CIN + ci) * N2G + (long long)gy * NGRID + gx;
        float vr = in ? xr[gi] : 0.0f;
        float vi = (INC && in) ? xi[gi] : 0.0f;
        tile[ci][ly][lx] = make_float2(vr, vi);
    }
    __syncthreads();

    int tx = threadIdx.x, ty = threadIdx.y;
    float accr[2][COUT], acci[2][COUT];
    #pragma unroll
    for (int h = 0; h < 2; ++h)
        #pragma unroll
        for (int co = 0; co < COUT; ++co) { accr[h][co] = 0.0f; acci[h][co] = 0.0f; }

    float isgn = conjt ? -1.0f : 1.0f;
    #pragma unroll 1
    for (int ci = 0; ci < CIN; ++ci) {
        #pragma unroll 1
        for (int p = 0; p < 3; ++p) {
            #pragma unroll
            for (int q = 0; q < 3; ++q) {
                float2 x0 = tile[ci][ty + p][tx + q];
                float2 x1 = tile[ci][ty + 16 + p][tx + q];
                #pragma unroll
                for (int co = 0; co < COUT; ++co) {
                    // wave-uniform index -> scalarized s_load (no LDS)
                    int widx = conjt
                        ? (b * wb + ci * ws1 + co * ws2 + q * 3 + p)
                        : (b * wb + co * ws1 + ci * ws2 + p * 3 + q);
                    float wx = wr[widx];
                    float wy = isgn * wi[widx];
                    accr[0][co] += wx * x0.x - wy * x0.y;
                    acci[0][co] += wx * x0.y + wy * x0.x;
                    accr[1][co] += wx * x1.x - wy * x1.y;
                    acci[1][co] += wx * x1.y + wy * x1.x;
                }
            }
        }
    }

    int gx = ox + tx;
    if (gx < NGRID) {
        #pragma unroll
        for (int h = 0; h < 2; ++h) {
            int gy = oy + ty + 16 * h;
            if (gy >= NGRID) continue;
            #pragma unroll
            for (int co = 0; co < COUT; ++co) {
                long long gi = (long long)(b * COUT + co) * N2G
                             + (long long)gy * NGRID + gx;
                yr[gi] = accr[h][co];
                yi[gi] = acci[h][co];
            }
        }
    }
}

// o *= wt * ik2  (complex multiply by wt, scale by ik2)
__global__ void k_scale(float* __restrict__ or_, float* __restrict__ oi_,
                        const float* __restrict__ wtr, const float* __restrict__ wti) {
    long long idx = (long long)blockIdx.x * blockDim.x + threadIdx.x;
    if (idx >= (long long)NB * N2G) return;
    int pix = (int)(idx % N2G);
    int u = pix / NGRID, v = pix % NGRID;
    int du = u - 256, dv = v - 256;
    float ik2;
    if (du == 0 && dv == 0)
        ik2 = 1.0f;
    else
        ik2 = (float)(1.0 / (9.869604401089358 * (double)(du * du + dv * dv)));
    float xr = or_[idx], xv = oi_[idx];
    float wrv = wtr[idx], wiv = wti[idx];
    or_[idx] = (xr * wrv - xv * wiv) * ik2;
    oi_[idx] = (xr * wiv + xv * wrv) * ik2;
}

// per-batch: red[2b] += sum(r*e), red[2b+1] += sum(Ae*e)
__global__ void k_dot2(const float* __restrict__ r, const float* __restrict__ e,
                       const float* __restrict__ Ae, float* __restrict__ red) {
    int b = blockIdx.y;
    const float* rb = r + (long long)b * N2G;
    const float* eb = e + (long long)b * N2G;
    const float* ab = Ae + (long long)b * N2G;
    float s1 = 0.0f, s2 = 0.0f;
    for (int i = blockIdx.x * blockDim.x + threadIdx.x; i < N2G;
         i += gridDim.x * blockDim.x) {
        float ev = eb[i];
        s1 += rb[i] * ev;
        s2 += ab[i] * ev;
    }
    #pragma unroll
    for (int o = 32; o > 0; o >>= 1) {
        s1 += __shfl_down(s1, o);
        s2 += __shfl_down(s2, o);
    }
    __shared__ float l1[4], l2[4];
    int wid = threadIdx.x >> 6;
    if ((threadIdx.x & 63) == 0) { l1[wid] = s1; l2[wid] = s2; }
    __syncthreads();
    if (threadIdx.x == 0) {
        atomicAdd(&red[2 * b], l1[0] + l1[1] + l1[2] + l1[3]);
        atomicAdd(&red[2 * b + 1], l2[0] + l2[1] + l2[2] + l2[3]);
    }
}

__global__ void k_update(float* __restrict__ x, const float* __restrict__ e,
                         const float* __restrict__ red) {
    long long idx = (long long)blockIdx.x * blockDim.x + threadIdx.x;
    if (idx >= (long long)NB * N2G) return;
    int b = (int)(idx / N2G);
    float alpha = red[2 * b] / red[2 * b + 1];
    x[idx] += alpha * e[idx];
}

__global__ void k_norm(const float* __restrict__ r, const float* __restrict__ f,
                       float* __restrict__ red) {
    float s1 = 0.0f, s2 = 0.0f;
    for (long long i = (long long)blockIdx.x * blockDim.x + threadIdx.x;
         i < (long long)NB * N2G; i += (long long)gridDim.x * blockDim.x) {
        float rv = r[i], fv = f[i];
        s1 += rv * rv;
        s2 += fv * fv;
    }
    #pragma unroll
    for (int o = 32; o > 0; o >>= 1) {
        s1 += __shfl_down(s1, o);
        s2 += __shfl_down(s2, o);
    }
    __shared__ float l1[4], l2[4];
    int wid = threadIdx.x >> 6;
    if ((threadIdx.x & 63) == 0) { l1[wid] = s1; l2[wid] = s2; }
    __syncthreads();
    if (threadIdx.x == 0) {
        atomicAdd(&red[8], l1[0] + l1[1] + l1[2] + l1[3]);
        atomicAdd(&red[9], l2[0] + l2[1] + l2[2] + l2[3]);
    }
}

__global__ void k_final(const float* __restrict__ red, float* __restrict__ out) {
    out[0] = sqrtf(red[8] / red[9]);
}

// ---------------------------------------------------------------------------
extern "C" void kernel_launch(void* const* d_in, const int* in_sizes, int n_in,
                              void* d_out, int out_size, void* d_ws, size_t ws_size,
                              hipStream_t stream) {
    (void)in_sizes; (void)n_in; (void)out_size; (void)ws_size;
    const float* f    = (const float*)d_in[0];
    const float* coef = (const float*)d_in[1];
    const float* w1r  = (const float*)d_in[3];
    const float* w1i  = (const float*)d_in[4];
    const float* w2r  = (const float*)d_in[5];
    const float* w2i  = (const float*)d_in[6];
    const float* w3r  = (const float*)d_in[7];
    const float* w3i  = (const float*)d_in[8];
    const float* wtr  = (const float*)d_in[9];
    const float* wti  = (const float*)d_in[10];
    float* out = (float*)d_out;

    float* ws = (float*)d_ws;
    size_t off = 0;
    auto alloc = [&](long long n) {
        float* p = ws + off;
        off += (size_t)((n + 3) & ~3LL);
        return p;
    };
    float* x0   = alloc((long long)NB * N2G);
    float* x1   = alloc((long long)NB * N2G);
    float* rr   = alloc((long long)NB * N2G);
    float* ee   = alloc((long long)NB * N2G);
    float* rh   = alloc((long long)NB * N2G);
    float* dinv = alloc((long long)NB * NI2);
    float* c1r  = alloc((long long)NB * 4 * N2G);
    float* c1i  = alloc((long long)NB * 4 * N2G);
    float* c2r  = alloc((long long)NB * 4 * N2G);
    float* c2i  = alloc((long long)NB * 4 * N2G);
    float* pr   = c1r;  // 32*N2G partial span (c1r..c1i..c2 contiguous)
    float* or_  = alloc((long long)NB * N2G);
    float* oi_  = alloc((long long)NB * N2G);
    float* red  = alloc(16);
    ushort* sGh  = (ushort*)alloc(513 * 512 / 2);
    ushort* sGl  = (ushort*)alloc(513 * 512 / 2);
    ushort* sGth = (ushort*)alloc(513 * 512 / 2);
    ushort* sGtl = (ushort*)alloc(513 * 512 / 2);
    ushort* sFAh = (ushort*)alloc(511 * 1056 / 2);
    ushort* sFAl = (ushort*)alloc(511 * 1056 / 2);
    ushort* sFBh = (ushort*)alloc(1022 * 1056 / 2);
    ushort* sFBl = (ushort*)alloc(1022 * 1056 / 2);
    ushort* dAh  = (ushort*)alloc((long long)NB * 513 * 1056 / 2);
    ushort* dAl  = (ushort*)alloc((long long)NB * 513 * 1056 / 2);
    ushort* dBh  = (ushort*)alloc((long long)NB * 511 * 1056 / 2);
    ushort* dBl  = (ushort*)alloc((long long)NB * 511 * 1056 / 2);
    float* Ae   = rh;  // rh is dead after the forward conv chain reads it

    dim3 blk2(16, 16);
    dim3 grdS(33, 33, NB);
    dim3 grdM(33, 17, NB);   // mcc: 16x32 output tile per block

    hipMemsetAsync(x0, 0, (size_t)NB * N2G * sizeof(float), stream);
    k_dinv<<<dim3((NB * NI2 + 255) / 256), dim3(256), 0, stream>>>(coef, dinv);
    k_genDSTA<<<dim3((513 * 512 + 255) / 256), dim3(256), 0, stream>>>(sGh, sGl);
    k_genDSTB<<<dim3((513 * 512 + 255) / 256), dim3(256), 0, stream>>>(sGth, sGtl);
    k_genFA<<<dim3((511 * 1056 + 255) / 256), dim3(256), 0, stream>>>(sFAh, sFAl);
    k_genFB<<<dim3((1022 * 1056 + 255) / 256), dim3(256), 0, stream>>>(sFBh, sFBl);

    float* xa = x0;
    float* xb = x1;
    for (int step = 0; step < 2; ++step) {
        // 10 weighted-Jacobi sweeps as 5 paired launches
        for (int it = 0; it < 5; ++it) {
            k_jacobi2<<<grdS, blk2, 0, stream>>>(xa, coef, f, dinv, xb);
            float* t = xa; xa = xb; xb = t;
        }
        k_stencil<<<grdS, blk2, 0, stream>>>(xa, coef, f, nullptr, rr, 0);

        // ---- H_apply (all GEMMs via MFMA split-bf16) ----
        // gemm1: t2 = G(513x511) * rI(511x511); B^T from rr interior
        k_cvtBt<<<dim3((511 * 512 + 255) / 256, NB), dim3(256), 0, stream>>>(
            rr + NGRID + 1, N2G, NGRID, 511, 511, 512, dBh, dBl);
        k_mgemm<<<dim3(4, 5, NB * 8), dim3(256), 0, stream>>>(
            sGh, sGl, 0, dBh, dBl, (long long)511 * 512,
            pr, (long long)NTT, 513, 511, 512, 8);
        // fused reduce + convert -> gemm2 A planes
        k_redA<<<dim3(1026, NB), dim3(256), 0, stream>>>(pr, 8, dAh, dAl);
        // gemm2: rh = t2(513x511) * Gt(511x513)
        k_mgemm<<<dim3(5, 5, NB * 8), dim3(256), 0, stream>>>(
            dAh, dAl, (long long)513 * 512, sGth, sGtl, 0,
            pr, (long long)N2G, 513, 513, 512, 8);
        k_reduce<<<dim3(1024, NB), dim3(256), 0, stream>>>(
            pr, rh, N2G, NGRID, NGRID, (long long)N2G, 8);
        // forward convs: w1 (1->4), w2 (4->4), w3 (4->1)
        k_mcc<1, 4, false><<<grdM, blk2, 0, stream>>>(rh, nullptr, w1r, w1i, c1r, c1i, 36, 9, 9, 0);
        k_mcc<4, 4, true><<<grdM, blk2, 0, stream>>>(c1r, c1i, w2r, w2i, c2r, c2i, 144, 36, 9, 0);
        k_mcc<4, 1, true><<<grdM, blk2, 0, stream>>>(c2r, c2i, w3r, w3i, or_, oi_, 36, 36, 9, 0);
        k_scale<<<dim3((NB * N2G + 255) / 256), dim3(256), 0, stream>>>(or_, oi_, wtr, wti);
        // adjoint convs
        k_mcc<1, 4, true><<<grdM, blk2, 0, stream>>>(or_, oi_, w3r, w3i, c1r, c1i, 36, 36, 9, 1);
        k_mcc<4, 4, true><<<grdM, blk2, 0, stream>>>(c1r, c1i, w2r, w2i, c2r, c2i, 144, 36, 9, 1);
        k_mcc<4, 1, true><<<grdM, blk2, 0, stream>>>(c2r, c2i, w1r, w1i, or_, oi_, 36, 9, 9, 1);
        // gemm3' (transposed): P'[n<1022][m<513] = sFB * [or|oi]^T
        k_cvtA<<<dim3((513 * 1056 + 255) / 256, NB), dim3(256), 0, stream>>>(
            or_, oi_, N2G, N2G, NGRID, NGRID, 513, 513, 1026, 1056, dAh, dAl);
        k_mgemm<<<dim3(5, 8, NB * 4), dim3(256), 0, stream>>>(
            sFBh, sFBl, 0, dAh, dAl, (long long)513 * 1056,
            pr, 1022LL * 513, 1022, 513, 1056, 4);
        // fused reduce + convert (+row-stack sign) -> gemm4 Bt planes
        k_redBt<<<dim3(2109, NB), dim3(256), 0, stream>>>(pr, 4, dBh, dBl);
        // gemm4: e = [Fr|Fi](511x1026) * [t2r;-t2i](1026x511)
        k_mgemm<<<dim3(4, 4, NB * 8), dim3(256), 0, stream>>>(
            sFAh, sFAl, 0, dBh, dBl, (long long)511 * 1056,
            pr, (long long)NI2, 511, 511, 1056, 8);
        hipMemsetAsync(ee, 0, (size_t)NB * N2G * sizeof(float), stream);
        k_reduce<<<dim3(1024, NB), dim3(256), 0, stream>>>(
            pr, ee + NGRID + 1, NI2, NINT, NGRID, (long long)N2G, 8);

        // Ae = A e ; alpha = (r.e)/(Ae.e) ; x += alpha e
        k_stencil<<<grdS, blk2, 0, stream>>>(ee, coef, nullptr, nullptr, Ae, 2);
        hipMemsetAsync(red, 0, 8 * sizeof(float), stream);
        k_dot2<<<dim3(64, NB), dim3(256), 0, stream>>>(rr, ee, Ae, red);
        k_update<<<dim3((NB * N2G + 255) / 256), dim3(256), 0, stream>>>(xa, ee, red);
    }
    k_stencil<<<grdS, blk2, 0, stream>>>(xa, coef, f, nullptr, rr, 0);
    hipMemsetAsync(red + 8, 0, 2 * sizeof(float), stream);
    k_norm<<<dim3(256), dim3(256), 0, stream>>>(rr, f, red);
    k_final<<<dim3(1), dim3(1), 0, stream>>>(red, out);
}

// Round 15
// 989.622 us; speedup vs baseline: 1.0625x; 1.0625x over previous
//
#include <hip/hip_runtime.h>
#include <math.h>

#ifndef M_PI
#define M_PI 3.14159265358979323846
#endif

#define NGRID 513
#define NCELL 512
#define NINT  511
#define NB    4

constexpr int N2G = NGRID * NGRID;   // 263169
constexpr int NI2 = NINT * NINT;     // 261121
constexpr int NTT = NGRID * NINT;    // 262143

typedef unsigned short ushort;
typedef __attribute__((ext_vector_type(8))) short short8;
typedef __attribute__((ext_vector_type(8))) unsigned short ushort8;
typedef __attribute__((ext_vector_type(4))) float f32x4;

// ---------------------------------------------------------------------------
// bf16 split helpers (RNE)
// ---------------------------------------------------------------------------
__device__ __forceinline__ ushort f2bf(float x) {
    unsigned u = __float_as_uint(x);
    unsigned r = u + 0x7FFFu + ((u >> 16) & 1u);
    return (ushort)(r >> 16);
}
__device__ __forceinline__ float bf2f(ushort h) {
    return __uint_as_float(((unsigned)h) << 16);
}

// ---------------------------------------------------------------------------
// FEM Darcy operator at interior node (i,j), i,j in 1..511
// ---------------------------------------------------------------------------
__device__ __forceinline__ float darcyA(const float* __restrict__ x,
                                        const float* __restrict__ a,
                                        int i, int j) {
    const float c23 = 2.0f / 3.0f, c16 = 1.0f / 6.0f, c13 = 1.0f / 3.0f;
    float a00 = a[(i - 1) * NCELL + (j - 1)];
    float a01 = a[(i - 1) * NCELL + j];
    float a10 = a[i * NCELL + (j - 1)];
    float a11 = a[i * NCELL + j];
    const float* xm = x + (i - 1) * NGRID;
    const float* xc = x + i * NGRID;
    const float* xp = x + (i + 1) * NGRID;
    return c23 * (a00 + a01 + a10 + a11) * xc[j]
         - c16 * ((a00 + a01) * xm[j] + (a10 + a11) * xp[j]
                + (a00 + a10) * xc[j - 1] + (a01 + a11) * xc[j + 1])
         - c13 * (a00 * xm[j - 1] + a01 * xm[j + 1]
                + a10 * xp[j - 1] + a11 * xp[j + 1]);
}

__global__ void k_stencil(const float* __restrict__ xin,
                          const float* __restrict__ a,
                          const float* __restrict__ f,
                          const float* __restrict__ dinv,
                          float* __restrict__ out, int mode) {
    int b = blockIdx.z;
    int j = blockIdx.x * 16 + threadIdx.x;
    int i = blockIdx.y * 16 + threadIdx.y;
    if (i >= NGRID || j >= NGRID) return;
    const float* xb = xin + (long long)b * N2G;
    const float* ab = a + (long long)b * NCELL * NCELL;
    long long idx = (long long)b * N2G + (long long)i * NGRID + j;
    bool interior = (i >= 1 && i <= NINT && j >= 1 && j <= NINT);
    if (!interior) {
        out[idx] = (mode == 0) ? f[idx] : 0.0f;
        return;
    }
    float Ax = darcyA(xb, ab, i, j);
    if (mode == 0) {
        out[idx] = f[idx] - Ax;
    } else {
        out[idx] = Ax;
    }
}

// ---------------------------------------------------------------------------
// Paired weighted-Jacobi: 2 sweeps per launch via LDS staging (halo 2).
// Bit-identical arithmetic to two k_stencil mode-1 passes.
// ---------------------------------------------------------------------------
__global__ void k_jacobi2(const float* __restrict__ xin,
                          const float* __restrict__ a,
                          const float* __restrict__ f,
                          const float* __restrict__ dinv,
                          float* __restrict__ out) {
    __shared__ float sx[20][20];
    __shared__ float sa[19][20];
    __shared__ float sf[18][18];
    __shared__ float sd[18][18];
    __shared__ float s1[18][20];
    const float c23 = 2.0f / 3.0f, c16 = 1.0f / 6.0f, c13 = 1.0f / 3.0f;
    int b = blockIdx.z;
    const float* xb = xin + (long long)b * N2G;
    const float* ab = a + (long long)b * NCELL * NCELL;
    const float* fb = f + (long long)b * N2G;
    const float* db = dinv + (long long)b * NI2;
    int ox = blockIdx.x * 16, oy = blockIdx.y * 16;
    int tx = threadIdx.x, ty = threadIdx.y;
    int tid = ty * 16 + tx;

    for (int idx = tid; idx < 400; idx += 256) {
        int ly = idx / 20, lx = idx % 20;
        int gy = oy - 2 + ly, gx = ox - 2 + lx;
        bool in = (gy >= 0 && gy < NGRID && gx >= 0 && gx < NGRID);
        sx[ly][lx] = in ? xb[(long long)gy * NGRID + gx] : 0.0f;
    }
    for (int idx = tid; idx < 361; idx += 256) {
        int ly = idx / 19, lx = idx % 19;
        int gy = oy - 2 + ly, gx = ox - 2 + lx;
        bool in = (gy >= 0 && gy < NCELL && gx >= 0 && gx < NCELL);
        sa[ly][lx] = in ? ab[(long long)gy * NCELL + gx] : 0.0f;
    }
    for (int idx = tid; idx < 324; idx += 256) {
        int ly = idx / 18, lx = idx % 18;
        int gy = oy - 1 + ly, gx = ox - 1 + lx;
        bool ing = (gy >= 0 && gy < NGRID && gx >= 0 && gx < NGRID);
        bool itr = (gy >= 1 && gy <= NINT && gx >= 1 && gx <= NINT);
        sf[ly][lx] = ing ? fb[(long long)gy * NGRID + gx] : 0.0f;
        sd[ly][lx] = itr ? db[(long long)(gy - 1) * NINT + (gx - 1)] : 0.0f;
    }
    __syncthreads();

    for (int idx = tid; idx < 324; idx += 256) {
        int ly = idx / 18, lx = idx % 18;
        int gy = oy - 1 + ly, gx = ox - 1 + lx;
        float v = 0.0f;
        if (gy >= 0 && gy < NGRID && gx >= 0 && gx < NGRID) {
            float xc = sx[ly + 1][lx + 1];
            if (gy >= 1 && gy <= NINT && gx >= 1 && gx <= NINT) {
                float a00 = sa[ly][lx], a01 = sa[ly][lx + 1];
                float a10 = sa[ly + 1][lx], a11 = sa[ly + 1][lx + 1];
                float Ax = c23 * (a00 + a01 + a10 + a11) * xc
                    - c16 * ((a00 + a01) * sx[ly][lx + 1] + (a10 + a11) * sx[ly + 2][lx + 1]
                           + (a00 + a10) * sx[ly + 1][lx] + (a01 + a11) * sx[ly + 1][lx + 2])
                    - c13 * (a00 * sx[ly][lx] + a01 * sx[ly][lx + 2]
                           + a10 * sx[ly + 2][lx] + a11 * sx[ly + 2][lx + 2]);
                v = xc + 0.75f * sd[ly][lx] * (sf[ly][lx] - Ax);
            } else {
                v = xc;
            }
        }
        s1[ly][lx] = v;
    }
    __syncthreads();

    int gy = oy + ty, gx = ox + tx;
    if (gy < NGRID && gx < NGRID) {
        float v;
        float xc = s1[ty + 1][tx + 1];
        if (gy >= 1 && gy <= NINT && gx >= 1 && gx <= NINT) {
            float a00 = sa[ty + 1][tx + 1], a01 = sa[ty + 1][tx + 2];
            float a10 = sa[ty + 2][tx + 1], a11 = sa[ty + 2][tx + 2];
            float Ax = c23 * (a00 + a01 + a10 + a11) * xc
                - c16 * ((a00 + a01) * s1[ty][tx + 1] + (a10 + a11) * s1[ty + 2][tx + 1]
                       + (a00 + a10) * s1[ty + 1][tx] + (a01 + a11) * s1[ty + 1][tx + 2])
                - c13 * (a00 * s1[ty][tx] + a01 * s1[ty][tx + 2]
                       + a10 * s1[ty + 2][tx] + a11 * s1[ty + 2][tx + 2]);
            v = xc + 0.75f * sd[ty + 1][tx + 1] * (sf[ty + 1][tx + 1] - Ax);
        } else {
            v = xc;
        }
        out[(long long)b * N2G + (long long)gy * NGRID + gx] = v;
    }
}

__global__ void k_dinv(const float* __restrict__ a, float* __restrict__ dinv) {
    long long idx = (long long)blockIdx.x * blockDim.x + threadIdx.x;
    if (idx >= (long long)NB * NI2) return;
    int b = (int)(idx / NI2);
    int rem = (int)(idx % NI2);
    int p = rem / NINT, q = rem % NINT;
    const float* ab = a + (long long)b * NCELL * NCELL;
    float s = ab[p * NCELL + q] + ab[p * NCELL + q + 1]
            + ab[(p + 1) * NCELL + q] + ab[(p + 1) * NCELL + q + 1];
    dinv[idx] = 1.0f / ((2.0f / 3.0f) * s);
}

// ---------------------------------------------------------------------------
// Static bf16 matrix generation (hi/lo planes, K-padded, integer arg reduce)
// ---------------------------------------------------------------------------
__device__ __forceinline__ void wsplit(double v, ushort* Dh, ushort* Dl, int idx) {
    float vf = (float)v;
    ushort h = f2bf(vf);
    Dh[idx] = h;
    Dl[idx] = f2bf(vf - bf2f(h));
}

__global__ void k_genDSTA(ushort* __restrict__ Dh, ushort* __restrict__ Dl) {
    int idx = blockIdx.x * 256 + threadIdx.x;
    if (idx >= 513 * 512) return;
    int u = idx / 512, k = idx % 512;
    double v = 0.0;
    if (k < 511) {
        int t = ((u - 256) * (k + 1)) % 1024;
        if (t < 0) t += 1024;
        v = sin((M_PI / 512.0) * (double)t);
    }
    wsplit(v, Dh, Dl, idx);
}

__global__ void k_genDSTB(ushort* __restrict__ Dh, ushort* __restrict__ Dl) {
    int idx = blockIdx.x * 256 + threadIdx.x;
    if (idx >= 513 * 512) return;
    int v = idx / 512, k = idx % 512;
    double val = 0.0;
    if (k < 511) {
        int t = ((v - 256) * (k + 1)) % 1024;
        if (t < 0) t += 1024;
        val = sin((M_PI / 512.0) * (double)t) * (-1.0 / 262144.0);
    }
    wsplit(val, Dh, Dl, idx);
}

__global__ void k_genFA(ushort* __restrict__ Dh, ushort* __restrict__ Dl) {
    int idx = blockIdx.x * 256 + threadIdx.x;
    if (idx >= 511 * 1056) return;
    int y = idx / 1056, k = idx % 1056;
    double v = 0.0;
    if (k < 1026) {
        int m = (k < 513) ? k : (k - 513);
        long t = ((long)y * (m - 255)) % 1025;
        if (t < 0) t += 1025;
        double ang = (2.0 * M_PI / 1025.0) * (double)t;
        v = (k < 513) ? cos(ang) : -sin(ang);
    }
    wsplit(v, Dh, Dl, idx);
}

__global__ void k_genFB(ushort* __restrict__ Dh, ushort* __restrict__ Dl) {
    int idx = blockIdx.x * 256 + threadIdx.x;
    if (idx >= 1022 * 1056) return;
    int n = idx / 1056, k = idx % 1056;
    double v = 0.0;
    if (k < 1026) {
        int m = (k < 513) ? k : (k - 513);
        int y = (n < 511) ? n : (n - 511);
        long t = ((long)y * (m - 255)) % 1025;
        if (t < 0) t += 1025;
        double ang = (2.0 * M_PI / 1025.0) * (double)t;
        bool ktop = (k < 513), nleft = (n < 511);
        if (ktop && nleft)        v = cos(ang);
        else if (ktop && !nleft)  v = -sin(ang);
        else if (!ktop && nleft)  v = sin(ang);
        else                      v = cos(ang);
    }
    wsplit(v, Dh, Dl, idx);
}

// ---------------------------------------------------------------------------
// Dynamic fp32 -> bf16 hi/lo conversion (inputs to gemm1 / gemm3).
// ---------------------------------------------------------------------------
__global__ void k_cvtA(const float* __restrict__ s1, const float* __restrict__ s2,
                       long long bs1, long long bs2, int ld1, int ld2, int S,
                       int M, int K, int Kp,
                       ushort* __restrict__ Dh, ushort* __restrict__ Dl) {
    int b = blockIdx.y;
    int idx = blockIdx.x * 256 + threadIdx.x;
    if (idx >= M * Kp) return;
    int m = idx / Kp, k = idx % Kp;
    float v = 0.0f;
    if (k < K)
        v = (k < S) ? s1[b * bs1 + (long long)m * ld1 + k]
                    : s2[b * bs2 + (long long)m * ld2 + (k - S)];
    long long o = (long long)b * M * Kp + idx;
    ushort h = f2bf(v);
    Dh[o] = h;
    Dl[o] = f2bf(v - bf2f(h));
}

__global__ void k_cvtBt(const float* __restrict__ s1,
                        long long bs1, int ld1,
                        int N, int K, int Kp,
                        ushort* __restrict__ Dh, ushort* __restrict__ Dl) {
    int b = blockIdx.y;
    int idx = blockIdx.x * 256 + threadIdx.x;
    if (idx >= N * Kp) return;
    int n = idx / Kp, k = idx % Kp;
    float v = 0.0f;
    if (k < K)
        v = s1[b * bs1 + (long long)k * ld1 + n];
    long long o = (long long)b * N * Kp + idx;
    ushort h = f2bf(v);
    Dh[o] = h;
    Dl[o] = f2bf(v - bf2f(h));
}

// ---------------------------------------------------------------------------
// Fused split-K reduce + bf16 convert (GEMM->GEMM handoffs).
// ---------------------------------------------------------------------------
__global__ void k_redA(const float* __restrict__ P, int nsplit,
                       ushort* __restrict__ Dh, ushort* __restrict__ Dl) {
    int b = blockIdx.y;
    int idx = blockIdx.x * 256 + threadIdx.x;
    if (idx >= 513 * 512) return;
    int m = idx / 512, k = idx % 512;
    float v = 0.0f;
    if (k < 511) {
        long long base = (long long)m * 511 + k;
        #pragma unroll 4
        for (int s = 0; s < nsplit; ++s)
            v += P[((long long)b * nsplit + s) * NTT + base];
    }
    long long o = (long long)b * 513 * 512 + idx;
    ushort h = f2bf(v);
    Dh[o] = h;
    Dl[o] = f2bf(v - bf2f(h));
}

__global__ void k_redBt(const float* __restrict__ P, int nsplit,
                        ushort* __restrict__ Dh, ushort* __restrict__ Dl) {
    int b = blockIdx.y;
    int idx = blockIdx.x * 256 + threadIdx.x;
    if (idx >= 511 * 1056) return;
    int n = idx / 1056, k = idx % 1056;
    float v = 0.0f;
    if (k < 1026) {
        int row = (k < 513) ? n : (511 + n);
        int col = (k < 513) ? k : (k - 513);
        long long base = (long long)row * 513 + col;
        float acc = 0.0f;
        #pragma unroll 4
        for (int s = 0; s < nsplit; ++s)
            acc += P[((long long)b * nsplit + s) * (1022LL * 513) + base];
        v = (k < 513) ? acc : -acc;
    }
    long long o = (long long)b * 511 * 1056 + idx;
    ushort h = f2bf(v);
    Dh[o] = h;
    Dl[o] = f2bf(v - bf2f(h));
}

// ---------------------------------------------------------------------------
// MFMA real GEMM, 3-term split-bf16 (hh + hl + lh), 16x16x32 bf16 MFMA.
// (unchanged from R8 — validated)
// ---------------------------------------------------------------------------
__global__ __launch_bounds__(256) void k_mgemm(
    const ushort* __restrict__ Ah, const ushort* __restrict__ Al, long long bsA,
    const ushort* __restrict__ Bh, const ushort* __restrict__ Bl, long long bsB,
    float* __restrict__ C, long long bsC,
    int M, int N, int Kp, int nsplit) {
    __shared__ ushort sAh[128 * 40];
    __shared__ ushort sAl[128 * 40];
    __shared__ ushort sBh[128 * 40];
    __shared__ ushort sBl[128 * 40];

    int bz = blockIdx.z, b = bz / nsplit, ks = bz % nsplit;
    int kchunk = (((Kp + nsplit - 1) / nsplit) + 31) & ~31;
    int kbeg = ks * kchunk;
    int kend = min(Kp, kbeg + kchunk);

    Ah += b * bsA; Al += b * bsA;
    Bh += b * bsB; Bl += b * bsB;
    C += ((long long)b * nsplit + ks) * bsC;

    int bm = blockIdx.y * 128, bn = blockIdx.x * 128;
    int tid = threadIdx.x;
    int wave = tid >> 6, lane = tid & 63;
    int wm = (wave >> 1) * 64, wn = (wave & 1) * 64;
    int quad = lane >> 4, l16 = lane & 15;

    f32x4 zf = {0.f, 0.f, 0.f, 0.f};
    f32x4 acc[4][4];
    #pragma unroll
    for (int i = 0; i < 4; ++i)
        #pragma unroll
        for (int j = 0; j < 4; ++j) acc[i][j] = zf;

    int srow = tid >> 2;
    int sk8 = (tid & 3) * 8;

    for (int kt = kbeg; kt < kend; kt += 32) {
        #pragma unroll
        for (int h = 0; h < 2; ++h) {
            int row = srow + 64 * h;
            ushort8 vh = {0, 0, 0, 0, 0, 0, 0, 0};
            ushort8 vl = {0, 0, 0, 0, 0, 0, 0, 0};
            int gm = bm + row;
            if (gm < M) {
                vh = *(const ushort8*)(Ah + (long long)gm * Kp + kt + sk8);
                vl = *(const ushort8*)(Al + (long long)gm * Kp + kt + sk8);
            }
            *(ushort8*)(sAh + row * 40 + sk8) = vh;
            *(ushort8*)(sAl + row * 40 + sk8) = vl;
            ushort8 wh = {0, 0, 0, 0, 0, 0, 0, 0};
            ushort8 wl = {0, 0, 0, 0, 0, 0, 0, 0};
            int gn = bn + row;
            if (gn < N) {
                wh = *(const ushort8*)(Bh + (long long)gn * Kp + kt + sk8);
                wl = *(const ushort8*)(Bl + (long long)gn * Kp + kt + sk8);
            }
            *(ushort8*)(sBh + row * 40 + sk8) = wh;
            *(ushort8*)(sBl + row * 40 + sk8) = wl;
        }
        __syncthreads();

        short8 afh[4], afl[4], bfh[4], bfl[4];
        #pragma unroll
        for (int t = 0; t < 4; ++t) {
            int ar = wm + t * 16 + l16;
            afh[t] = *(const short8*)(sAh + ar * 40 + quad * 8);
            afl[t] = *(const short8*)(sAl + ar * 40 + quad * 8);
            int br = wn + t * 16 + l16;
            bfh[t] = *(const short8*)(sBh + br * 40 + quad * 8);
            bfl[t] = *(const short8*)(sBl + br * 40 + quad * 8);
        }
        #pragma unroll
        for (int mt = 0; mt < 4; ++mt)
            #pragma unroll
            for (int nt = 0; nt < 4; ++nt) {
                acc[mt][nt] = __builtin_amdgcn_mfma_f32_16x16x32_bf16(
                    afh[mt], bfh[nt], acc[mt][nt], 0, 0, 0);
                acc[mt][nt] = __builtin_amdgcn_mfma_f32_16x16x32_bf16(
                    afh[mt], bfl[nt], acc[mt][nt], 0, 0, 0);
                acc[mt][nt] = __builtin_amdgcn_mfma_f32_16x16x32_bf16(
                    afl[mt], bfh[nt], acc[mt][nt], 0, 0, 0);
            }
        __syncthreads();
    }

    #pragma unroll
    for (int mt = 0; mt < 4; ++mt) {
        #pragma unroll
        for (int r = 0; r < 4; ++r) {
            int gm = bm + wm + mt * 16 + quad * 4 + r;
            if (gm >= M) continue;
            long long rowoff = (long long)gm * N;
            #pragma unroll
            for (int nt = 0; nt < 4; ++nt) {
                int gn = bn + wn + nt * 16 + l16;
                if (gn < N) C[rowoff + gn] = acc[mt][nt][r];
            }
        }
    }
}

// ---------------------------------------------------------------------------
// Sum nsplit dense [M x N] partials -> strided fp32 output (row stride ldo).
// ---------------------------------------------------------------------------
__global__ void k_reduce(const float* __restrict__ Pr,
                         float* __restrict__ outR,
                         int MN, int N, int ldo, long long bsOut, int nsplit) {
    int b = blockIdx.y;
    for (int idx = blockIdx.x * 256 + threadIdx.x; idx < MN;
         idx += gridDim.x * 256) {
        float sr = 0.0f;
        #pragma unroll 4
        for (int s = 0; s < nsplit; ++s)
            sr += Pr[((long long)b * nsplit + s) * MN + idx];
        int m = idx / N, n = idx - m * N;
        outR[(long long)b * bsOut + (long long)m * ldo + n] = sr;
    }
}

// ---------------------------------------------------------------------------
// Complex multi-channel 3x3 conv (R13 configuration — validated best: LDS
// weights + float2 tiles, 2 px/thread, unroll-1 ci/p; VGPR 40, occ 40%,
// 47 us for 4->4. R14's scalarized global weights regressed: per-iter
// s_load + lgkmcnt stall, VALUBusy 53->42%.)
// ---------------------------------------------------------------------------
template <int CIN, int COUT, bool INC>
__global__ __launch_bounds__(256) void k_mcc(
    const float* __restrict__ xr, const float* __restrict__ xi,
    const float* __restrict__ wr, const float* __restrict__ wi,
    float* __restrict__ yr, float* __restrict__ yi,
    int wb, int ws1, int ws2, int conjt) {
    __shared__ float2 tile[CIN][34][18];
    __shared__ float2 wl[COUT * CIN * 9];
    int b = blockIdx.z;
    int tid = threadIdx.y * 16 + threadIdx.x;

    for (int idx = tid; idx < COUT * CIN * 9; idx += 256) {
        int co = idx / (CIN * 9);
        int r2 = idx % (CIN * 9);
        int ci = r2 / 9, s = r2 % 9;
        int p = s / 3, q = s % 3;
        int widx = conjt ? (b * wb + ci * ws1 + co * ws2 + q * 3 + p)
                         : (b * wb + co * ws1 + ci * ws2 + p * 3 + q);
        float iv = wi[widx];
        wl[idx] = make_float2(wr[widx], conjt ? -iv : iv);
    }
    int ox = blockIdx.x * 16, oy = blockIdx.y * 32;
    for (int idx = tid; idx < CIN * 34 * 18; idx += 256) {
        int ci = idx / (34 * 18), r2 = idx % (34 * 18);
        int ly = r2 / 18, lx = r2 % 18;
        int gy = oy + ly - 1, gx = ox + lx - 1;
        bool in = (gy >= 0 && gy < NGRID && gx >= 0 && gx < NGRID);
        long long gi = (long long)(b * CIN + ci) * N2G + (long long)gy * NGRID + gx;
        float vr = in ? xr[gi] : 0.0f;
        float vi = (INC && in) ? xi[gi] : 0.0f;
        tile[ci][ly][lx] = make_float2(vr, vi);
    }
    __syncthreads();

    int tx = threadIdx.x, ty = threadIdx.y;
    float accr[2][COUT], acci[2][COUT];
    #pragma unroll
    for (int h = 0; h < 2; ++h)
        #pragma unroll
        for (int co = 0; co < COUT; ++co) { accr[h][co] = 0.0f; acci[h][co] = 0.0f; }

    #pragma unroll 1
    for (int ci = 0; ci < CIN; ++ci) {
        #pragma unroll 1
        for (int p = 0; p < 3; ++p) {
            #pragma unroll
            for (int q = 0; q < 3; ++q) {
                float2 x0 = tile[ci][ty + p][tx + q];
                float2 x1 = tile[ci][ty + 16 + p][tx + q];
                #pragma unroll
                for (int co = 0; co < COUT; ++co) {
                    float2 w = wl[(co * CIN + ci) * 9 + p * 3 + q];
                    accr[0][co] += w.x * x0.x - w.y * x0.y;
                    acci[0][co] += w.x * x0.y + w.y * x0.x;
                    accr[1][co] += w.x * x1.x - w.y * x1.y;
                    acci[1][co] += w.x * x1.y + w.y * x1.x;
                }
            }
        }
    }

    int gx = ox + tx;
    if (gx < NGRID) {
        #pragma unroll
        for (int h = 0; h < 2; ++h) {
            int gy = oy + ty + 16 * h;
            if (gy >= NGRID) continue;
            #pragma unroll
            for (int co = 0; co < COUT; ++co) {
                long long gi = (long long)(b * COUT + co) * N2G
                             + (long long)gy * NGRID + gx;
                yr[gi] = accr[h][co];
                yi[gi] = acci[h][co];
            }
        }
    }
}

// o *= wt * ik2  (complex multiply by wt, scale by ik2)
__global__ void k_scale(float* __restrict__ or_, float* __restrict__ oi_,
                        const float* __restrict__ wtr, const float* __restrict__ wti) {
    long long idx = (long long)blockIdx.x * blockDim.x + threadIdx.x;
    if (idx >= (long long)NB * N2G) return;
    int pix = (int)(idx % N2G);
    int u = pix / NGRID, v = pix % NGRID;
    int du = u - 256, dv = v - 256;
    float ik2;
    if (du == 0 && dv == 0)
        ik2 = 1.0f;
    else
        ik2 = (float)(1.0 / (9.869604401089358 * (double)(du * du + dv * dv)));
    float xr = or_[idx], xv = oi_[idx];
    float wrv = wtr[idx], wiv = wti[idx];
    or_[idx] = (xr * wrv - xv * wiv) * ik2;
    oi_[idx] = (xr * wiv + xv * wrv) * ik2;
}

// per-batch: red[2b] += sum(r*e), red[2b+1] += sum(Ae*e)
__global__ void k_dot2(const float* __restrict__ r, const float* __restrict__ e,
                       const float* __restrict__ Ae, float* __restrict__ red) {
    int b = blockIdx.y;
    const float* rb = r + (long long)b * N2G;
    const float* eb = e + (long long)b * N2G;
    const float* ab = Ae + (long long)b * N2G;
    float s1 = 0.0f, s2 = 0.0f;
    for (int i = blockIdx.x * blockDim.x + threadIdx.x; i < N2G;
         i += gridDim.x * blockDim.x) {
        float ev = eb[i];
        s1 += rb[i] * ev;
        s2 += ab[i] * ev;
    }
    #pragma unroll
    for (int o = 32; o > 0; o >>= 1) {
        s1 += __shfl_down(s1, o);
        s2 += __shfl_down(s2, o);
    }
    __shared__ float l1[4], l2[4];
    int wid = threadIdx.x >> 6;
    if ((threadIdx.x & 63) == 0) { l1[wid] = s1; l2[wid] = s2; }
    __syncthreads();
    if (threadIdx.x == 0) {
        atomicAdd(&red[2 * b], l1[0] + l1[1] + l1[2] + l1[3]);
        atomicAdd(&red[2 * b + 1], l2[0] + l2[1] + l2[2] + l2[3]);
    }
}

__global__ void k_update(float* __restrict__ x, const float* __restrict__ e,
                         const float* __restrict__ red) {
    long long idx = (long long)blockIdx.x * blockDim.x + threadIdx.x;
    if (idx >= (long long)NB * N2G) return;
    int b = (int)(idx / N2G);
    float alpha = red[2 * b] / red[2 * b + 1];
    x[idx] += alpha * e[idx];
}

__global__ void k_norm(const float* __restrict__ r, const float* __restrict__ f,
                       float* __restrict__ red) {
    float s1 = 0.0f, s2 = 0.0f;
    for (long long i = (long long)blockIdx.x * blockDim.x + threadIdx.x;
         i < (long long)NB * N2G; i += (long long)gridDim.x * blockDim.x) {
        float rv = r[i], fv = f[i];
        s1 += rv * rv;
        s2 += fv * fv;
    }
    #pragma unroll
    for (int o = 32; o > 0; o >>= 1) {
        s1 += __shfl_down(s1, o);
        s2 += __shfl_down(s2, o);
    }
    __shared__ float l1[4], l2[4];
    int wid = threadIdx.x >> 6;
    if ((threadIdx.x & 63) == 0) { l1[wid] = s1; l2[wid] = s2; }
    __syncthreads();
    if (threadIdx.x == 0) {
        atomicAdd(&red[8], l1[0] + l1[1] + l1[2] + l1[3]);
        atomicAdd(&red[9], l2[0] + l2[1] + l2[2] + l2[3]);
    }
}

__global__ void k_final(const float* __restrict__ red, float* __restrict__ out) {
    out[0] = sqrtf(red[8] / red[9]);
}

// ---------------------------------------------------------------------------
extern "C" void kernel_launch(void* const* d_in, const int* in_sizes, int n_in,
                              void* d_out, int out_size, void* d_ws, size_t ws_size,
                              hipStream_t stream) {
    (void)in_sizes; (void)n_in; (void)out_size; (void)ws_size;
    const float* f    = (const float*)d_in[0];
    const float* coef = (const float*)d_in[1];
    const float* w1r  = (const float*)d_in[3];
    const float* w1i  = (const float*)d_in[4];
    const float* w2r  = (const float*)d_in[5];
    const float* w2i  = (const float*)d_in[6];
    const float* w3r  = (const float*)d_in[7];
    const float* w3i  = (const float*)d_in[8];
    const float* wtr  = (const float*)d_in[9];
    const float* wti  = (const float*)d_in[10];
    float* out = (float*)d_out;

    float* ws = (float*)d_ws;
    size_t off = 0;
    auto alloc = [&](long long n) {
        float* p = ws + off;
        off += (size_t)((n + 3) & ~3LL);
        return p;
    };
    float* x0   = alloc((long long)NB * N2G);
    float* x1   = alloc((long long)NB * N2G);
    float* rr   = alloc((long long)NB * N2G);
    float* ee   = alloc((long long)NB * N2G);
    float* rh   = alloc((long long)NB * N2G);
    float* dinv = alloc((long long)NB * NI2);
    float* c1r  = alloc((long long)NB * 4 * N2G);
    float* c1i  = alloc((long long)NB * 4 * N2G);
    float* c2r  = alloc((long long)NB * 4 * N2G);
    float* c2i  = alloc((long long)NB * 4 * N2G);
    float* pr   = c1r;  // partial span (c1r..c2i contiguous)
    float* or_  = alloc((long long)NB * N2G);
    float* oi_  = alloc((long long)NB * N2G);
    float* red  = alloc(16);
    ushort* sGh  = (ushort*)alloc(513 * 512 / 2);
    ushort* sGl  = (ushort*)alloc(513 * 512 / 2);
    ushort* sGth = (ushort*)alloc(513 * 512 / 2);
    ushort* sGtl = (ushort*)alloc(513 * 512 / 2);
    ushort* sFAh = (ushort*)alloc(511 * 1056 / 2);
    ushort* sFAl = (ushort*)alloc(511 * 1056 / 2);
    ushort* sFBh = (ushort*)alloc(1022 * 1056 / 2);
    ushort* sFBl = (ushort*)alloc(1022 * 1056 / 2);
    ushort* dAh  = (ushort*)alloc((long long)NB * 513 * 1056 / 2);
    ushort* dAl  = (ushort*)alloc((long long)NB * 513 * 1056 / 2);
    ushort* dBh  = (ushort*)alloc((long long)NB * 511 * 1056 / 2);
    ushort* dBl  = (ushort*)alloc((long long)NB * 511 * 1056 / 2);
    float* Ae   = rh;  // rh is dead after the forward conv chain reads it

    dim3 blk2(16, 16);
    dim3 grdS(33, 33, NB);
    dim3 grdM(33, 17, NB);   // mcc: 16x32 output tile per block
    const int SP = 4;        // split-K (R15: 8->4 halves partial traffic;
                             // grids stay >=256 blocks)

    hipMemsetAsync(x0, 0, (size_t)NB * N2G * sizeof(float), stream);
    k_dinv<<<dim3((NB * NI2 + 255) / 256), dim3(256), 0, stream>>>(coef, dinv);
    k_genDSTA<<<dim3((513 * 512 + 255) / 256), dim3(256), 0, stream>>>(sGh, sGl);
    k_genDSTB<<<dim3((513 * 512 + 255) / 256), dim3(256), 0, stream>>>(sGth, sGtl);
    k_genFA<<<dim3((511 * 1056 + 255) / 256), dim3(256), 0, stream>>>(sFAh, sFAl);
    k_genFB<<<dim3((1022 * 1056 + 255) / 256), dim3(256), 0, stream>>>(sFBh, sFBl);

    float* xa = x0;
    float* xb = x1;
    for (int step = 0; step < 2; ++step) {
        // 10 weighted-Jacobi sweeps as 5 paired launches
        for (int it = 0; it < 5; ++it) {
            k_jacobi2<<<grdS, blk2, 0, stream>>>(xa, coef, f, dinv, xb);
            float* t = xa; xa = xb; xb = t;
        }
        k_stencil<<<grdS, blk2, 0, stream>>>(xa, coef, f, nullptr, rr, 0);

        // ---- H_apply (all GEMMs via MFMA split-bf16) ----
        // gemm1: t2 = G(513x511) * rI(511x511); B^T from rr interior
        k_cvtBt<<<dim3((511 * 512 + 255) / 256, NB), dim3(256), 0, stream>>>(
            rr + NGRID + 1, N2G, NGRID, 511, 511, 512, dBh, dBl);
        k_mgemm<<<dim3(4, 5, NB * SP), dim3(256), 0, stream>>>(
            sGh, sGl, 0, dBh, dBl, (long long)511 * 512,
            pr, (long long)NTT, 513, 511, 512, SP);
        // fused reduce + convert -> gemm2 A planes
        k_redA<<<dim3(1026, NB), dim3(256), 0, stream>>>(pr, SP, dAh, dAl);
        // gemm2: rh = t2(513x511) * Gt(511x513)
        k_mgemm<<<dim3(5, 5, NB * SP), dim3(256), 0, stream>>>(
            dAh, dAl, (long long)513 * 512, sGth, sGtl, 0,
            pr, (long long)N2G, 513, 513, 512, SP);
        k_reduce<<<dim3(1024, NB), dim3(256), 0, stream>>>(
            pr, rh, N2G, NGRID, NGRID, (long long)N2G, SP);
        // forward convs: w1 (1->4), w2 (4->4), w3 (4->1)
        k_mcc<1, 4, false><<<grdM, blk2, 0, stream>>>(rh, nullptr, w1r, w1i, c1r, c1i, 36, 9, 9, 0);
        k_mcc<4, 4, true><<<grdM, blk2, 0, stream>>>(c1r, c1i, w2r, w2i, c2r, c2i, 144, 36, 9, 0);
        k_mcc<4, 1, true><<<grdM, blk2, 0, stream>>>(c2r, c2i, w3r, w3i, or_, oi_, 36, 36, 9, 0);
        k_scale<<<dim3((NB * N2G + 255) / 256), dim3(256), 0, stream>>>(or_, oi_, wtr, wti);
        // adjoint convs
        k_mcc<1, 4, true><<<grdM, blk2, 0, stream>>>(or_, oi_, w3r, w3i, c1r, c1i, 36, 36, 9, 1);
        k_mcc<4, 4, true><<<grdM, blk2, 0, stream>>>(c1r, c1i, w2r, w2i, c2r, c2i, 144, 36, 9, 1);
        k_mcc<4, 1, true><<<grdM, blk2, 0, stream>>>(c2r, c2i, w1r, w1i, or_, oi_, 36, 9, 9, 1);
        // gemm3' (transposed): P'[n<1022][m<513] = sFB * [or|oi]^T
        k_cvtA<<<dim3((513 * 1056 + 255) / 256, NB), dim3(256), 0, stream>>>(
            or_, oi_, N2G, N2G, NGRID, NGRID, 513, 513, 1026, 1056, dAh, dAl);
        k_mgemm<<<dim3(5, 8, NB * 4), dim3(256), 0, stream>>>(
            sFBh, sFBl, 0, dAh, dAl, (long long)513 * 1056,
            pr, 1022LL * 513, 1022, 513, 1056, 4);
        // fused reduce + convert (+row-stack sign) -> gemm4 Bt planes
        k_redBt<<<dim3(2109, NB), dim3(256), 0, stream>>>(pr, 4, dBh, dBl);
        // gemm4: e = [Fr|Fi](511x1026) * [t2r;-t2i](1026x511)
        k_mgemm<<<dim3(4, 4, NB * SP), dim3(256), 0, stream>>>(
            sFAh, sFAl, 0, dBh, dBl, (long long)511 * 1056,
            pr, (long long)NI2, 511, 511, 1056, SP);
        hipMemsetAsync(ee, 0, (size_t)NB * N2G * sizeof(float), stream);
        k_reduce<<<dim3(1024, NB), dim3(256), 0, stream>>>(
            pr, ee + NGRID + 1, NI2, NINT, NGRID, (long long)N2G, SP);

        // Ae = A e ; alpha = (r.e)/(Ae.e) ; x += alpha e
        k_stencil<<<grdS, blk2, 0, stream>>>(ee, coef, nullptr, nullptr, Ae, 2);
        hipMemsetAsync(red, 0, 8 * sizeof(float), stream);
        k_dot2<<<dim3(64, NB), dim3(256), 0, stream>>>(rr, ee, Ae, red);
        k_update<<<dim3((NB * N2G + 255) / 256), dim3(256), 0, stream>>>(xa, ee, red);
    }
    k_stencil<<<grdS, blk2, 0, stream>>>(xa, coef, f, nullptr, rr, 0);
    hipMemsetAsync(red + 8, 0, 2 * sizeof(float), stream);
    k_norm<<<dim3(256), dim3(256), 0, stream>>>(rr, f, red);
    k_final<<<dim3(1), dim3(1), 0, stream>>>(red, out);
}

// Round 16
// 917.512 us; speedup vs baseline: 1.1460x; 1.0786x over previous
//
#include <hip/hip_runtime.h>
#include <math.h>

#ifndef M_PI
#define M_PI 3.14159265358979323846
#endif

#define NGRID 513
#define NCELL 512
#define NINT  511
#define NB    4

constexpr int N2G = NGRID * NGRID;   // 263169
constexpr int NI2 = NINT * NINT;     // 261121
constexpr int NTT = NGRID * NINT;    // 262143

typedef unsigned short ushort;
typedef unsigned int uint32;
typedef __attribute__((ext_vector_type(8))) short short8;
typedef __attribute__((ext_vector_type(8))) unsigned short ushort8;
typedef __attribute__((ext_vector_type(4))) float f32x4;

// ---------------------------------------------------------------------------
// bf16 split helpers (RNE)
// ---------------------------------------------------------------------------
__device__ __forceinline__ ushort f2bf(float x) {
    unsigned u = __float_as_uint(x);
    unsigned r = u + 0x7FFFu + ((u >> 16) & 1u);
    return (ushort)(r >> 16);
}
__device__ __forceinline__ float bf2f(ushort h) {
    return __uint_as_float(((unsigned)h) << 16);
}

// ---------------------------------------------------------------------------
// FEM Darcy operator at interior node (i,j), i,j in 1..511
// ---------------------------------------------------------------------------
__device__ __forceinline__ float darcyA(const float* __restrict__ x,
                                        const float* __restrict__ a,
                                        int i, int j) {
    const float c23 = 2.0f / 3.0f, c16 = 1.0f / 6.0f, c13 = 1.0f / 3.0f;
    float a00 = a[(i - 1) * NCELL + (j - 1)];
    float a01 = a[(i - 1) * NCELL + j];
    float a10 = a[i * NCELL + (j - 1)];
    float a11 = a[i * NCELL + j];
    const float* xm = x + (i - 1) * NGRID;
    const float* xc = x + i * NGRID;
    const float* xp = x + (i + 1) * NGRID;
    return c23 * (a00 + a01 + a10 + a11) * xc[j]
         - c16 * ((a00 + a01) * xm[j] + (a10 + a11) * xp[j]
                + (a00 + a10) * xc[j - 1] + (a01 + a11) * xc[j + 1])
         - c13 * (a00 * xm[j - 1] + a01 * xm[j + 1]
                + a10 * xp[j - 1] + a11 * xp[j + 1]);
}

__global__ void k_stencil(const float* __restrict__ xin,
                          const float* __restrict__ a,
                          const float* __restrict__ f,
                          const float* __restrict__ dinv,
                          float* __restrict__ out, int mode) {
    int b = blockIdx.z;
    int j = blockIdx.x * 16 + threadIdx.x;
    int i = blockIdx.y * 16 + threadIdx.y;
    if (i >= NGRID || j >= NGRID) return;
    const float* xb = xin + (long long)b * N2G;
    const float* ab = a + (long long)b * NCELL * NCELL;
    long long idx = (long long)b * N2G + (long long)i * NGRID + j;
    bool interior = (i >= 1 && i <= NINT && j >= 1 && j <= NINT);
    if (!interior) {
        out[idx] = (mode == 0) ? f[idx] : 0.0f;
        return;
    }
    float Ax = darcyA(xb, ab, i, j);
    if (mode == 0) {
        out[idx] = f[idx] - Ax;
    } else {
        out[idx] = Ax;
    }
}

// ---------------------------------------------------------------------------
// Paired weighted-Jacobi: 2 sweeps per launch via LDS staging (halo 2).
// Bit-identical arithmetic to two k_stencil mode-1 passes.
// ---------------------------------------------------------------------------
__global__ void k_jacobi2(const float* __restrict__ xin,
                          const float* __restrict__ a,
                          const float* __restrict__ f,
                          const float* __restrict__ dinv,
                          float* __restrict__ out) {
    __shared__ float sx[20][20];
    __shared__ float sa[19][20];
    __shared__ float sf[18][18];
    __shared__ float sd[18][18];
    __shared__ float s1[18][20];
    const float c23 = 2.0f / 3.0f, c16 = 1.0f / 6.0f, c13 = 1.0f / 3.0f;
    int b = blockIdx.z;
    const float* xb = xin + (long long)b * N2G;
    const float* ab = a + (long long)b * NCELL * NCELL;
    const float* fb = f + (long long)b * N2G;
    const float* db = dinv + (long long)b * NI2;
    int ox = blockIdx.x * 16, oy = blockIdx.y * 16;
    int tx = threadIdx.x, ty = threadIdx.y;
    int tid = ty * 16 + tx;

    for (int idx = tid; idx < 400; idx += 256) {
        int ly = idx / 20, lx = idx % 20;
        int gy = oy - 2 + ly, gx = ox - 2 + lx;
        bool in = (gy >= 0 && gy < NGRID && gx >= 0 && gx < NGRID);
        sx[ly][lx] = in ? xb[(long long)gy * NGRID + gx] : 0.0f;
    }
    for (int idx = tid; idx < 361; idx += 256) {
        int ly = idx / 19, lx = idx % 19;
        int gy = oy - 2 + ly, gx = ox - 2 + lx;
        bool in = (gy >= 0 && gy < NCELL && gx >= 0 && gx < NCELL);
        sa[ly][lx] = in ? ab[(long long)gy * NCELL + gx] : 0.0f;
    }
    for (int idx = tid; idx < 324; idx += 256) {
        int ly = idx / 18, lx = idx % 18;
        int gy = oy - 1 + ly, gx = ox - 1 + lx;
        bool ing = (gy >= 0 && gy < NGRID && gx >= 0 && gx < NGRID);
        bool itr = (gy >= 1 && gy <= NINT && gx >= 1 && gx <= NINT);
        sf[ly][lx] = ing ? fb[(long long)gy * NGRID + gx] : 0.0f;
        sd[ly][lx] = itr ? db[(long long)(gy - 1) * NINT + (gx - 1)] : 0.0f;
    }
    __syncthreads();

    for (int idx = tid; idx < 324; idx += 256) {
        int ly = idx / 18, lx = idx % 18;
        int gy = oy - 1 + ly, gx = ox - 1 + lx;
        float v = 0.0f;
        if (gy >= 0 && gy < NGRID && gx >= 0 && gx < NGRID) {
            float xc = sx[ly + 1][lx + 1];
            if (gy >= 1 && gy <= NINT && gx >= 1 && gx <= NINT) {
                float a00 = sa[ly][lx], a01 = sa[ly][lx + 1];
                float a10 = sa[ly + 1][lx], a11 = sa[ly + 1][lx + 1];
                float Ax = c23 * (a00 + a01 + a10 + a11) * xc
                    - c16 * ((a00 + a01) * sx[ly][lx + 1] + (a10 + a11) * sx[ly + 2][lx + 1]
                           + (a00 + a10) * sx[ly + 1][lx] + (a01 + a11) * sx[ly + 1][lx + 2])
                    - c13 * (a00 * sx[ly][lx] + a01 * sx[ly][lx + 2]
                           + a10 * sx[ly + 2][lx] + a11 * sx[ly + 2][lx + 2]);
                v = xc + 0.75f * sd[ly][lx] * (sf[ly][lx] - Ax);
            } else {
                v = xc;
            }
        }
        s1[ly][lx] = v;
    }
    __syncthreads();

    int gy = oy + ty, gx = ox + tx;
    if (gy < NGRID && gx < NGRID) {
        float v;
        float xc = s1[ty + 1][tx + 1];
        if (gy >= 1 && gy <= NINT && gx >= 1 && gx <= NINT) {
            float a00 = sa[ty + 1][tx + 1], a01 = sa[ty + 1][tx + 2];
            float a10 = sa[ty + 2][tx + 1], a11 = sa[ty + 2][tx + 2];
            float Ax = c23 * (a00 + a01 + a10 + a11) * xc
                - c16 * ((a00 + a01) * s1[ty][tx + 1] + (a10 + a11) * s1[ty + 2][tx + 1]
                       + (a00 + a10) * s1[ty + 1][tx] + (a01 + a11) * s1[ty + 1][tx + 2])
                - c13 * (a00 * s1[ty][tx] + a01 * s1[ty][tx + 2]
                       + a10 * s1[ty + 2][tx] + a11 * s1[ty + 2][tx + 2]);
            v = xc + 0.75f * sd[ty + 1][tx + 1] * (sf[ty + 1][tx + 1] - Ax);
        } else {
            v = xc;
        }
        out[(long long)b * N2G + (long long)gy * NGRID + gx] = v;
    }
}

__global__ void k_dinv(const float* __restrict__ a, float* __restrict__ dinv) {
    long long idx = (long long)blockIdx.x * blockDim.x + threadIdx.x;
    if (idx >= (long long)NB * NI2) return;
    int b = (int)(idx / NI2);
    int rem = (int)(idx % NI2);
    int p = rem / NINT, q = rem % NINT;
    const float* ab = a + (long long)b * NCELL * NCELL;
    float s = ab[p * NCELL + q] + ab[p * NCELL + q + 1]
            + ab[(p + 1) * NCELL + q] + ab[(p + 1) * NCELL + q + 1];
    dinv[idx] = 1.0f / ((2.0f / 3.0f) * s);
}

// ---------------------------------------------------------------------------
// Static bf16 matrix generation (hi/lo planes, K-padded, integer arg reduce)
// ---------------------------------------------------------------------------
__device__ __forceinline__ void wsplit(double v, ushort* Dh, ushort* Dl, int idx) {
    float vf = (float)v;
    ushort h = f2bf(vf);
    Dh[idx] = h;
    Dl[idx] = f2bf(vf - bf2f(h));
}

__global__ void k_genDSTA(ushort* __restrict__ Dh, ushort* __restrict__ Dl) {
    int idx = blockIdx.x * 256 + threadIdx.x;
    if (idx >= 513 * 512) return;
    int u = idx / 512, k = idx % 512;
    double v = 0.0;
    if (k < 511) {
        int t = ((u - 256) * (k + 1)) % 1024;
        if (t < 0) t += 1024;
        v = sin((M_PI / 512.0) * (double)t);
    }
    wsplit(v, Dh, Dl, idx);
}

__global__ void k_genDSTB(ushort* __restrict__ Dh, ushort* __restrict__ Dl) {
    int idx = blockIdx.x * 256 + threadIdx.x;
    if (idx >= 513 * 512) return;
    int v = idx / 512, k = idx % 512;
    double val = 0.0;
    if (k < 511) {
        int t = ((v - 256) * (k + 1)) % 1024;
        if (t < 0) t += 1024;
        val = sin((M_PI / 512.0) * (double)t) * (-1.0 / 262144.0);
    }
    wsplit(val, Dh, Dl, idx);
}

__global__ void k_genFA(ushort* __restrict__ Dh, ushort* __restrict__ Dl) {
    int idx = blockIdx.x * 256 + threadIdx.x;
    if (idx >= 511 * 1056) return;
    int y = idx / 1056, k = idx % 1056;
    double v = 0.0;
    if (k < 1026) {
        int m = (k < 513) ? k : (k - 513);
        long t = ((long)y * (m - 255)) % 1025;
        if (t < 0) t += 1025;
        double ang = (2.0 * M_PI / 1025.0) * (double)t;
        v = (k < 513) ? cos(ang) : -sin(ang);
    }
    wsplit(v, Dh, Dl, idx);
}

__global__ void k_genFB(ushort* __restrict__ Dh, ushort* __restrict__ Dl) {
    int idx = blockIdx.x * 256 + threadIdx.x;
    if (idx >= 1022 * 1056) return;
    int n = idx / 1056, k = idx % 1056;
    double v = 0.0;
    if (k < 1026) {
        int m = (k < 513) ? k : (k - 513);
        int y = (n < 511) ? n : (n - 511);
        long t = ((long)y * (m - 255)) % 1025;
        if (t < 0) t += 1025;
        double ang = (2.0 * M_PI / 1025.0) * (double)t;
        bool ktop = (k < 513), nleft = (n < 511);
        if (ktop && nleft)        v = cos(ang);
        else if (ktop && !nleft)  v = -sin(ang);
        else if (!ktop && nleft)  v = sin(ang);
        else                      v = cos(ang);
    }
    wsplit(v, Dh, Dl, idx);
}

// ---------------------------------------------------------------------------
// Dynamic fp32 -> bf16 hi/lo conversion (inputs to gemm1 / gemm3).
// ---------------------------------------------------------------------------
__global__ void k_cvtA(const float* __restrict__ s1, const float* __restrict__ s2,
                       long long bs1, long long bs2, int ld1, int ld2, int S,
                       int M, int K, int Kp,
                       ushort* __restrict__ Dh, ushort* __restrict__ Dl) {
    int b = blockIdx.y;
    int idx = blockIdx.x * 256 + threadIdx.x;
    if (idx >= M * Kp) return;
    int m = idx / Kp, k = idx % Kp;
    float v = 0.0f;
    if (k < K)
        v = (k < S) ? s1[b * bs1 + (long long)m * ld1 + k]
                    : s2[b * bs2 + (long long)m * ld2 + (k - S)];
    long long o = (long long)b * M * Kp + idx;
    ushort h = f2bf(v);
    Dh[o] = h;
    Dl[o] = f2bf(v - bf2f(h));
}

__global__ void k_cvtBt(const float* __restrict__ s1,
                        long long bs1, int ld1,
                        int N, int K, int Kp,
                        ushort* __restrict__ Dh, ushort* __restrict__ Dl) {
    int b = blockIdx.y;
    int idx = blockIdx.x * 256 + threadIdx.x;
    if (idx >= N * Kp) return;
    int n = idx / Kp, k = idx % Kp;
    float v = 0.0f;
    if (k < K)
        v = s1[b * bs1 + (long long)k * ld1 + n];
    long long o = (long long)b * N * Kp + idx;
    ushort h = f2bf(v);
    Dh[o] = h;
    Dl[o] = f2bf(v - bf2f(h));
}

// ---------------------------------------------------------------------------
// Fused split-K reduce + bf16 convert (GEMM->GEMM handoffs).
// ---------------------------------------------------------------------------
__global__ void k_redA(const float* __restrict__ P, int nsplit,
                       ushort* __restrict__ Dh, ushort* __restrict__ Dl) {
    int b = blockIdx.y;
    int idx = blockIdx.x * 256 + threadIdx.x;
    if (idx >= 513 * 512) return;
    int m = idx / 512, k = idx % 512;
    float v = 0.0f;
    if (k < 511) {
        long long base = (long long)m * 511 + k;
        #pragma unroll 4
        for (int s = 0; s < nsplit; ++s)
            v += P[((long long)b * nsplit + s) * NTT + base];
    }
    long long o = (long long)b * 513 * 512 + idx;
    ushort h = f2bf(v);
    Dh[o] = h;
    Dl[o] = f2bf(v - bf2f(h));
}

__global__ void k_redBt(const float* __restrict__ P, int nsplit,
                        ushort* __restrict__ Dh, ushort* __restrict__ Dl) {
    int b = blockIdx.y;
    int idx = blockIdx.x * 256 + threadIdx.x;
    if (idx >= 511 * 1056) return;
    int n = idx / 1056, k = idx % 1056;
    float v = 0.0f;
    if (k < 1026) {
        int row = (k < 513) ? n : (511 + n);
        int col = (k < 513) ? k : (k - 513);
        long long base = (long long)row * 513 + col;
        float acc = 0.0f;
        #pragma unroll 4
        for (int s = 0; s < nsplit; ++s)
            acc += P[((long long)b * nsplit + s) * (1022LL * 513) + base];
        v = (k < 513) ? acc : -acc;
    }
    long long o = (long long)b * 511 * 1056 + idx;
    ushort h = f2bf(v);
    Dh[o] = h;
    Dl[o] = f2bf(v - bf2f(h));
}

// ---------------------------------------------------------------------------
// MFMA real GEMM, 3-term split-bf16 (hh + hl + lh), 16x16x32 bf16 MFMA.
// (unchanged from R8 — validated)
// ---------------------------------------------------------------------------
__global__ __launch_bounds__(256) void k_mgemm(
    const ushort* __restrict__ Ah, const ushort* __restrict__ Al, long long bsA,
    const ushort* __restrict__ Bh, const ushort* __restrict__ Bl, long long bsB,
    float* __restrict__ C, long long bsC,
    int M, int N, int Kp, int nsplit) {
    __shared__ ushort sAh[128 * 40];
    __shared__ ushort sAl[128 * 40];
    __shared__ ushort sBh[128 * 40];
    __shared__ ushort sBl[128 * 40];

    int bz = blockIdx.z, b = bz / nsplit, ks = bz % nsplit;
    int kchunk = (((Kp + nsplit - 1) / nsplit) + 31) & ~31;
    int kbeg = ks * kchunk;
    int kend = min(Kp, kbeg + kchunk);

    Ah += b * bsA; Al += b * bsA;
    Bh += b * bsB; Bl += b * bsB;
    C += ((long long)b * nsplit + ks) * bsC;

    int bm = blockIdx.y * 128, bn = blockIdx.x * 128;
    int tid = threadIdx.x;
    int wave = tid >> 6, lane = tid & 63;
    int wm = (wave >> 1) * 64, wn = (wave & 1) * 64;
    int quad = lane >> 4, l16 = lane & 15;

    f32x4 zf = {0.f, 0.f, 0.f, 0.f};
    f32x4 acc[4][4];
    #pragma unroll
    for (int i = 0; i < 4; ++i)
        #pragma unroll
        for (int j = 0; j < 4; ++j) acc[i][j] = zf;

    int srow = tid >> 2;
    int sk8 = (tid & 3) * 8;

    for (int kt = kbeg; kt < kend; kt += 32) {
        #pragma unroll
        for (int h = 0; h < 2; ++h) {
            int row = srow + 64 * h;
            ushort8 vh = {0, 0, 0, 0, 0, 0, 0, 0};
            ushort8 vl = {0, 0, 0, 0, 0, 0, 0, 0};
            int gm = bm + row;
            if (gm < M) {
                vh = *(const ushort8*)(Ah + (long long)gm * Kp + kt + sk8);
                vl = *(const ushort8*)(Al + (long long)gm * Kp + kt + sk8);
            }
            *(ushort8*)(sAh + row * 40 + sk8) = vh;
            *(ushort8*)(sAl + row * 40 + sk8) = vl;
            ushort8 wh = {0, 0, 0, 0, 0, 0, 0, 0};
            ushort8 wl = {0, 0, 0, 0, 0, 0, 0, 0};
            int gn = bn + row;
            if (gn < N) {
                wh = *(const ushort8*)(Bh + (long long)gn * Kp + kt + sk8);
                wl = *(const ushort8*)(Bl + (long long)gn * Kp + kt + sk8);
            }
            *(ushort8*)(sBh + row * 40 + sk8) = wh;
            *(ushort8*)(sBl + row * 40 + sk8) = wl;
        }
        __syncthreads();

        short8 afh[4], afl[4], bfh[4], bfl[4];
        #pragma unroll
        for (int t = 0; t < 4; ++t) {
            int ar = wm + t * 16 + l16;
            afh[t] = *(const short8*)(sAh + ar * 40 + quad * 8);
            afl[t] = *(const short8*)(sAl + ar * 40 + quad * 8);
            int br = wn + t * 16 + l16;
            bfh[t] = *(const short8*)(sBh + br * 40 + quad * 8);
            bfl[t] = *(const short8*)(sBl + br * 40 + quad * 8);
        }
        #pragma unroll
        for (int mt = 0; mt < 4; ++mt)
            #pragma unroll
            for (int nt = 0; nt < 4; ++nt) {
                acc[mt][nt] = __builtin_amdgcn_mfma_f32_16x16x32_bf16(
                    afh[mt], bfh[nt], acc[mt][nt], 0, 0, 0);
                acc[mt][nt] = __builtin_amdgcn_mfma_f32_16x16x32_bf16(
                    afh[mt], bfl[nt], acc[mt][nt], 0, 0, 0);
                acc[mt][nt] = __builtin_amdgcn_mfma_f32_16x16x32_bf16(
                    afl[mt], bfh[nt], acc[mt][nt], 0, 0, 0);
            }
        __syncthreads();
    }

    #pragma unroll
    for (int mt = 0; mt < 4; ++mt) {
        #pragma unroll
        for (int r = 0; r < 4; ++r) {
            int gm = bm + wm + mt * 16 + quad * 4 + r;
            if (gm >= M) continue;
            long long rowoff = (long long)gm * N;
            #pragma unroll
            for (int nt = 0; nt < 4; ++nt) {
                int gn = bn + wn + nt * 16 + l16;
                if (gn < N) C[rowoff + gn] = acc[mt][nt][r];
            }
        }
    }
}

// ---------------------------------------------------------------------------
// Sum nsplit dense [M x N] partials -> strided fp32 output (row stride ldo).
// ---------------------------------------------------------------------------
__global__ void k_reduce(const float* __restrict__ Pr,
                         float* __restrict__ outR,
                         int MN, int N, int ldo, long long bsOut, int nsplit) {
    int b = blockIdx.y;
    for (int idx = blockIdx.x * 256 + threadIdx.x; idx < MN;
         idx += gridDim.x * 256) {
        float sr = 0.0f;
        #pragma unroll 4
        for (int s = 0; s < nsplit; ++s)
            sr += Pr[((long long)b * nsplit + s) * MN + idx];
        int m = idx / N, n = idx - m * N;
        outR[(long long)b * bsOut + (long long)m * ldo + n] = sr;
    }
}

// ---------------------------------------------------------------------------
// Complex multi-channel 3x3 conv (R16 = R13 compute + packed-bf16 I/O for
// intermediates): BFIN/BFOUT select a packed uint {bf16 re | bf16 im} per
// pixel-channel. Unpack at staging is 2 VALU (v<<16, v&0xffff0000); pack at
// store is 2 cvt + or. Halves the conv chain's global traffic (the R15
// co-limiter: 101 MB at 2.1 TB/s alongside VALU 54%). Compute core and
// LDS float2 tiles identical to R13 (validated best).
// ---------------------------------------------------------------------------
template <int CIN, int COUT, bool INC, bool BFIN, bool BFOUT>
__global__ __launch_bounds__(256) void k_mcc(
    const float* __restrict__ xr, const float* __restrict__ xi,
    const float* __restrict__ wr, const float* __restrict__ wi,
    float* __restrict__ yr, float* __restrict__ yi,
    int wb, int ws1, int ws2, int conjt) {
    __shared__ float2 tile[CIN][34][18];
    __shared__ float2 wl[COUT * CIN * 9];
    int b = blockIdx.z;
    int tid = threadIdx.y * 16 + threadIdx.x;

    for (int idx = tid; idx < COUT * CIN * 9; idx += 256) {
        int co = idx / (CIN * 9);
        int r2 = idx % (CIN * 9);
        int ci = r2 / 9, s = r2 % 9;
        int p = s / 3, q = s % 3;
        int widx = conjt ? (b * wb + ci * ws1 + co * ws2 + q * 3 + p)
                         : (b * wb + co * ws1 + ci * ws2 + p * 3 + q);
        float iv = wi[widx];
        wl[idx] = make_float2(wr[widx], conjt ? -iv : iv);
    }
    int ox = blockIdx.x * 16, oy = blockIdx.y * 32;
    for (int idx = tid; idx < CIN * 34 * 18; idx += 256) {
        int ci = idx / (34 * 18), r2 = idx % (34 * 18);
        int ly = r2 / 18, lx = r2 % 18;
        int gy = oy + ly - 1, gx = ox + lx - 1;
        bool in = (gy >= 0 && gy < NGRID && gx >= 0 && gx < NGRID);
        long long gi = (long long)(b * CIN + ci) * N2G + (long long)gy * NGRID + gx;
        float vr, vi;
        if (BFIN) {
            const uint32* xp = (const uint32*)xr;
            uint32 v = in ? xp[gi] : 0u;
            vr = __uint_as_float(v << 16);
            vi = __uint_as_float(v & 0xffff0000u);
        } else {
            vr = in ? xr[gi] : 0.0f;
            vi = (INC && in) ? xi[gi] : 0.0f;
        }
        tile[ci][ly][lx] = make_float2(vr, vi);
    }
    __syncthreads();

    int tx = threadIdx.x, ty = threadIdx.y;
    float accr[2][COUT], acci[2][COUT];
    #pragma unroll
    for (int h = 0; h < 2; ++h)
        #pragma unroll
        for (int co = 0; co < COUT; ++co) { accr[h][co] = 0.0f; acci[h][co] = 0.0f; }

    #pragma unroll 1
    for (int ci = 0; ci < CIN; ++ci) {
        #pragma unroll 1
        for (int p = 0; p < 3; ++p) {
            #pragma unroll
            for (int q = 0; q < 3; ++q) {
                float2 x0 = tile[ci][ty + p][tx + q];
                float2 x1 = tile[ci][ty + 16 + p][tx + q];
                #pragma unroll
                for (int co = 0; co < COUT; ++co) {
                    float2 w = wl[(co * CIN + ci) * 9 + p * 3 + q];
                    accr[0][co] += w.x * x0.x - w.y * x0.y;
                    acci[0][co] += w.x * x0.y + w.y * x0.x;
                    accr[1][co] += w.x * x1.x - w.y * x1.y;
                    acci[1][co] += w.x * x1.y + w.y * x1.x;
                }
            }
        }
    }

    int gx = ox + tx;
    if (gx < NGRID) {
        #pragma unroll
        for (int h = 0; h < 2; ++h) {
            int gy = oy + ty + 16 * h;
            if (gy >= NGRID) continue;
            #pragma unroll
            for (int co = 0; co < COUT; ++co) {
                long long gi = (long long)(b * COUT + co) * N2G
                             + (long long)gy * NGRID + gx;
                if (BFOUT) {
                    uint32* yp = (uint32*)yr;
                    uint32 v = ((uint32)f2bf(acci[h][co]) << 16)
                             | (uint32)f2bf(accr[h][co]);
                    yp[gi] = v;
                } else {
                    yr[gi] = accr[h][co];
                    yi[gi] = acci[h][co];
                }
            }
        }
    }
}

// o *= wt * ik2  (complex multiply by wt, scale by ik2)
__global__ void k_scale(float* __restrict__ or_, float* __restrict__ oi_,
                        const float* __restrict__ wtr, const float* __restrict__ wti) {
    long long idx = (long long)blockIdx.x * blockDim.x + threadIdx.x;
    if (idx >= (long long)NB * N2G) return;
    int pix = (int)(idx % N2G);
    int u = pix / NGRID, v = pix % NGRID;
    int du = u - 256, dv = v - 256;
    float ik2;
    if (du == 0 && dv == 0)
        ik2 = 1.0f;
    else
        ik2 = (float)(1.0 / (9.869604401089358 * (double)(du * du + dv * dv)));
    float xr = or_[idx], xv = oi_[idx];
    float wrv = wtr[idx], wiv = wti[idx];
    or_[idx] = (xr * wrv - xv * wiv) * ik2;
    oi_[idx] = (xr * wiv + xv * wrv) * ik2;
}

// per-batch: red[2b] += sum(r*e), red[2b+1] += sum(Ae*e)
__global__ void k_dot2(const float* __restrict__ r, const float* __restrict__ e,
                       const float* __restrict__ Ae, float* __restrict__ red) {
    int b = blockIdx.y;
    const float* rb = r + (long long)b * N2G;
    const float* eb = e + (long long)b * N2G;
    const float* ab = Ae + (long long)b * N2G;
    float s1 = 0.0f, s2 = 0.0f;
    for (int i = blockIdx.x * blockDim.x + threadIdx.x; i < N2G;
         i += gridDim.x * blockDim.x) {
        float ev = eb[i];
        s1 += rb[i] * ev;
        s2 += ab[i] * ev;
    }
    #pragma unroll
    for (int o = 32; o > 0; o >>= 1) {
        s1 += __shfl_down(s1, o);
        s2 += __shfl_down(s2, o);
    }
    __shared__ float l1[4], l2[4];
    int wid = threadIdx.x >> 6;
    if ((threadIdx.x & 63) == 0) { l1[wid] = s1; l2[wid] = s2; }
    __syncthreads();
    if (threadIdx.x == 0) {
        atomicAdd(&red[2 * b], l1[0] + l1[1] + l1[2] + l1[3]);
        atomicAdd(&red[2 * b + 1], l2[0] + l2[1] + l2[2] + l2[3]);
    }
}

__global__ void k_update(float* __restrict__ x, const float* __restrict__ e,
                         const float* __restrict__ red) {
    long long idx = (long long)blockIdx.x * blockDim.x + threadIdx.x;
    if (idx >= (long long)NB * N2G) return;
    int b = (int)(idx / N2G);
    float alpha = red[2 * b] / red[2 * b + 1];
    x[idx] += alpha * e[idx];
}

__global__ void k_norm(const float* __restrict__ r, const float* __restrict__ f,
                       float* __restrict__ red) {
    float s1 = 0.0f, s2 = 0.0f;
    for (long long i = (long long)blockIdx.x * blockDim.x + threadIdx.x;
         i < (long long)NB * N2G; i += (long long)gridDim.x * blockDim.x) {
        float rv = r[i], fv = f[i];
        s1 += rv * rv;
        s2 += fv * fv;
    }
    #pragma unroll
    for (int o = 32; o > 0; o >>= 1) {
        s1 += __shfl_down(s1, o);
        s2 += __shfl_down(s2, o);
    }
    __shared__ float l1[4], l2[4];
    int wid = threadIdx.x >> 6;
    if ((threadIdx.x & 63) == 0) { l1[wid] = s1; l2[wid] = s2; }
    __syncthreads();
    if (threadIdx.x == 0) {
        atomicAdd(&red[8], l1[0] + l1[1] + l1[2] + l1[3]);
        atomicAdd(&red[9], l2[0] + l2[1] + l2[2] + l2[3]);
    }
}

__global__ void k_final(const float* __restrict__ red, float* __restrict__ out) {
    out[0] = sqrtf(red[8] / red[9]);
}

// ---------------------------------------------------------------------------
extern "C" void kernel_launch(void* const* d_in, const int* in_sizes, int n_in,
                              void* d_out, int out_size, void* d_ws, size_t ws_size,
                              hipStream_t stream) {
    (void)in_sizes; (void)n_in; (void)out_size; (void)ws_size;
    const float* f    = (const float*)d_in[0];
    const float* coef = (const float*)d_in[1];
    const float* w1r  = (const float*)d_in[3];
    const float* w1i  = (const float*)d_in[4];
    const float* w2r  = (const float*)d_in[5];
    const float* w2i  = (const float*)d_in[6];
    const float* w3r  = (const float*)d_in[7];
    const float* w3i  = (const float*)d_in[8];
    const float* wtr  = (const float*)d_in[9];
    const float* wti  = (const float*)d_in[10];
    float* out = (float*)d_out;

    float* ws = (float*)d_ws;
    size_t off = 0;
    auto alloc = [&](long long n) {
        float* p = ws + off;
        off += (size_t)((n + 3) & ~3LL);
        return p;
    };
    float* x0   = alloc((long long)NB * N2G);
    float* x1   = alloc((long long)NB * N2G);
    float* rr   = alloc((long long)NB * N2G);
    float* ee   = alloc((long long)NB * N2G);
    float* rh   = alloc((long long)NB * N2G);
    float* dinv = alloc((long long)NB * NI2);
    float* c1r  = alloc((long long)NB * 4 * N2G);
    float* c1i  = alloc((long long)NB * 4 * N2G);
    float* c2r  = alloc((long long)NB * 4 * N2G);
    float* c2i  = alloc((long long)NB * 4 * N2G);
    float* pr   = c1r;  // partial span (c1r..c2i contiguous)
    float* c1pk = c1r;  // packed bf16 conv intermediate 1 (uint per px-ch)
    float* c2pk = c2r;  // packed bf16 conv intermediate 2
    float* or_  = alloc((long long)NB * N2G);
    float* oi_  = alloc((long long)NB * N2G);
    float* red  = alloc(16);
    ushort* sGh  = (ushort*)alloc(513 * 512 / 2);
    ushort* sGl  = (ushort*)alloc(513 * 512 / 2);
    ushort* sGth = (ushort*)alloc(513 * 512 / 2);
    ushort* sGtl = (ushort*)alloc(513 * 512 / 2);
    ushort* sFAh = (ushort*)alloc(511 * 1056 / 2);
    ushort* sFAl = (ushort*)alloc(511 * 1056 / 2);
    ushort* sFBh = (ushort*)alloc(1022 * 1056 / 2);
    ushort* sFBl = (ushort*)alloc(1022 * 1056 / 2);
    ushort* dAh  = (ushort*)alloc((long long)NB * 513 * 1056 / 2);
    ushort* dAl  = (ushort*)alloc((long long)NB * 513 * 1056 / 2);
    ushort* dBh  = (ushort*)alloc((long long)NB * 511 * 1056 / 2);
    ushort* dBl  = (ushort*)alloc((long long)NB * 511 * 1056 / 2);
    float* Ae   = rh;  // rh is dead after the forward conv chain reads it

    dim3 blk2(16, 16);
    dim3 grdS(33, 33, NB);
    dim3 grdM(33, 17, NB);   // mcc: 16x32 output tile per block
    const int SP = 4;        // split-K (validated R15)

    hipMemsetAsync(x0, 0, (size_t)NB * N2G * sizeof(float), stream);
    k_dinv<<<dim3((NB * NI2 + 255) / 256), dim3(256), 0, stream>>>(coef, dinv);
    k_genDSTA<<<dim3((513 * 512 + 255) / 256), dim3(256), 0, stream>>>(sGh, sGl);
    k_genDSTB<<<dim3((513 * 512 + 255) / 256), dim3(256), 0, stream>>>(sGth, sGtl);
    k_genFA<<<dim3((511 * 1056 + 255) / 256), dim3(256), 0, stream>>>(sFAh, sFAl);
    k_genFB<<<dim3((1022 * 1056 + 255) / 256), dim3(256), 0, stream>>>(sFBh, sFBl);

    float* xa = x0;
    float* xb = x1;
    for (int step = 0; step < 2; ++step) {
        // 10 weighted-Jacobi sweeps as 5 paired launches
        for (int it = 0; it < 5; ++it) {
            k_jacobi2<<<grdS, blk2, 0, stream>>>(xa, coef, f, dinv, xb);
            float* t = xa; xa = xb; xb = t;
        }
        k_stencil<<<grdS, blk2, 0, stream>>>(xa, coef, f, nullptr, rr, 0);

        // ---- H_apply (all GEMMs via MFMA split-bf16) ----
        // gemm1: t2 = G(513x511) * rI(511x511); B^T from rr interior
        k_cvtBt<<<dim3((511 * 512 + 255) / 256, NB), dim3(256), 0, stream>>>(
            rr + NGRID + 1, N2G, NGRID, 511, 511, 512, dBh, dBl);
        k_mgemm<<<dim3(4, 5, NB * SP), dim3(256), 0, stream>>>(
            sGh, sGl, 0, dBh, dBl, (long long)511 * 512,
            pr, (long long)NTT, 513, 511, 512, SP);
        // fused reduce + convert -> gemm2 A planes
        k_redA<<<dim3(1026, NB), dim3(256), 0, stream>>>(pr, SP, dAh, dAl);
        // gemm2: rh = t2(513x511) * Gt(511x513)
        k_mgemm<<<dim3(5, 5, NB * SP), dim3(256), 0, stream>>>(
            dAh, dAl, (long long)513 * 512, sGth, sGtl, 0,
            pr, (long long)N2G, 513, 513, 512, SP);
        k_reduce<<<dim3(1024, NB), dim3(256), 0, stream>>>(
            pr, rh, N2G, NGRID, NGRID, (long long)N2G, SP);
        // forward convs: w1 (1->4), w2 (4->4), w3 (4->1); c1/c2 packed bf16
        k_mcc<1, 4, false, false, true><<<grdM, blk2, 0, stream>>>(
            rh, nullptr, w1r, w1i, c1pk, nullptr, 36, 9, 9, 0);
        k_mcc<4, 4, true, true, true><<<grdM, blk2, 0, stream>>>(
            c1pk, nullptr, w2r, w2i, c2pk, nullptr, 144, 36, 9, 0);
        k_mcc<4, 1, true, true, false><<<grdM, blk2, 0, stream>>>(
            c2pk, nullptr, w3r, w3i, or_, oi_, 36, 36, 9, 0);
        k_scale<<<dim3((NB * N2G + 255) / 256), dim3(256), 0, stream>>>(or_, oi_, wtr, wti);
        // adjoint convs
        k_mcc<1, 4, true, false, true><<<grdM, blk2, 0, stream>>>(
            or_, oi_, w3r, w3i, c1pk, nullptr, 36, 36, 9, 1);
        k_mcc<4, 4, true, true, true><<<grdM, blk2, 0, stream>>>(
            c1pk, nullptr, w2r, w2i, c2pk, nullptr, 144, 36, 9, 1);
        k_mcc<4, 1, true, true, false><<<grdM, blk2, 0, stream>>>(
            c2pk, nullptr, w1r, w1i, or_, oi_, 36, 9, 9, 1);
        // gemm3' (transposed): P'[n<1022][m<513] = sFB * [or|oi]^T
        k_cvtA<<<dim3((513 * 1056 + 255) / 256, NB), dim3(256), 0, stream>>>(
            or_, oi_, N2G, N2G, NGRID, NGRID, 513, 513, 1026, 1056, dAh, dAl);
        k_mgemm<<<dim3(5, 8, NB * 4), dim3(256), 0, stream>>>(
            sFBh, sFBl, 0, dAh, dAl, (long long)513 * 1056,
            pr, 1022LL * 513, 1022, 513, 1056, 4);
        // fused reduce + convert (+row-stack sign) -> gemm4 Bt planes
        k_redBt<<<dim3(2109, NB), dim3(256), 0, stream>>>(pr, 4, dBh, dBl);
        // gemm4: e = [Fr|Fi](511x1026) * [t2r;-t2i](1026x511)
        k_mgemm<<<dim3(4, 4, NB * SP), dim3(256), 0, stream>>>(
            sFAh, sFAl, 0, dBh, dBl, (long long)511 * 1056,
            pr, (long long)NI2, 511, 511, 1056, SP);
        hipMemsetAsync(ee, 0, (size_t)NB * N2G * sizeof(float), stream);
        k_reduce<<<dim3(1024, NB), dim3(256), 0, stream>>>(
            pr, ee + NGRID + 1, NI2, NINT, NGRID, (long long)N2G, SP);

        // Ae = A e ; alpha = (r.e)/(Ae.e) ; x += alpha e
        k_stencil<<<grdS, blk2, 0, stream>>>(ee, coef, nullptr, nullptr, Ae, 2);
        hipMemsetAsync(red, 0, 8 * sizeof(float), stream);
        k_dot2<<<dim3(64, NB), dim3(256), 0, stream>>>(rr, ee, Ae, red);
        k_update<<<dim3((NB * N2G + 255) / 256), dim3(256), 0, stream>>>(xa, ee, red);
    }
    k_stencil<<<grdS, blk2, 0, stream>>>(xa, coef, f, nullptr, rr, 0);
    hipMemsetAsync(red + 8, 0, 2 * sizeof(float), stream);
    k_norm<<<dim3(256), dim3(256), 0, stream>>>(rr, f, red);
    k_final<<<dim3(1), dim3(1), 0, stream>>>(red, out);
}

// Round 17
// 873.433 us; speedup vs baseline: 1.2038x; 1.0505x over previous
//
#include <hip/hip_runtime.h>
#include <math.h>

#ifndef M_PI
#define M_PI 3.14159265358979323846
#endif

#define NGRID 513
#define NCELL 512
#define NINT  511
#define NB    4

constexpr int N2G = NGRID * NGRID;   // 263169
constexpr int NI2 = NINT * NINT;     // 261121
constexpr int NTT = NGRID * NINT;    // 262143

typedef unsigned short ushort;
typedef unsigned int uint32;
typedef __attribute__((ext_vector_type(8))) short short8;
typedef __attribute__((ext_vector_type(8))) unsigned short ushort8;
typedef __attribute__((ext_vector_type(4))) float f32x4;

// ---------------------------------------------------------------------------
// bf16 split helpers (RNE)
// ---------------------------------------------------------------------------
__device__ __forceinline__ ushort f2bf(float x) {
    unsigned u = __float_as_uint(x);
    unsigned r = u + 0x7FFFu + ((u >> 16) & 1u);
    return (ushort)(r >> 16);
}
__device__ __forceinline__ float bf2f(ushort h) {
    return __uint_as_float(((unsigned)h) << 16);
}

// ---------------------------------------------------------------------------
// FEM Darcy operator at interior node (i,j), i,j in 1..511
// ---------------------------------------------------------------------------
__device__ __forceinline__ float darcyA(const float* __restrict__ x,
                                        const float* __restrict__ a,
                                        int i, int j) {
    const float c23 = 2.0f / 3.0f, c16 = 1.0f / 6.0f, c13 = 1.0f / 3.0f;
    float a00 = a[(i - 1) * NCELL + (j - 1)];
    float a01 = a[(i - 1) * NCELL + j];
    float a10 = a[i * NCELL + (j - 1)];
    float a11 = a[i * NCELL + j];
    const float* xm = x + (i - 1) * NGRID;
    const float* xc = x + i * NGRID;
    const float* xp = x + (i + 1) * NGRID;
    return c23 * (a00 + a01 + a10 + a11) * xc[j]
         - c16 * ((a00 + a01) * xm[j] + (a10 + a11) * xp[j]
                + (a00 + a10) * xc[j - 1] + (a01 + a11) * xc[j + 1])
         - c13 * (a00 * xm[j - 1] + a01 * xm[j + 1]
                + a10 * xp[j - 1] + a11 * xp[j + 1]);
}

__global__ void k_stencil(const float* __restrict__ xin,
                          const float* __restrict__ a,
                          const float* __restrict__ f,
                          const float* __restrict__ dinv,
                          float* __restrict__ out, int mode) {
    int b = blockIdx.z;
    int j = blockIdx.x * 16 + threadIdx.x;
    int i = blockIdx.y * 16 + threadIdx.y;
    if (i >= NGRID || j >= NGRID) return;
    const float* xb = xin + (long long)b * N2G;
    const float* ab = a + (long long)b * NCELL * NCELL;
    long long idx = (long long)b * N2G + (long long)i * NGRID + j;
    bool interior = (i >= 1 && i <= NINT && j >= 1 && j <= NINT);
    if (!interior) {
        out[idx] = (mode == 0) ? f[idx] : 0.0f;
        return;
    }
    float Ax = darcyA(xb, ab, i, j);
    if (mode == 0) {
        out[idx] = f[idx] - Ax;
    } else {
        out[idx] = Ax;
    }
}

// ---------------------------------------------------------------------------
// 5 fused weighted-Jacobi sweeps per launch (halo 5, LDS ping-pong stages).
// Per-sweep arithmetic identical to the validated jacobi2 (same FMA order,
// same zero-pad / boundary-copy semantics). ~15 KB LDS -> >=8 blocks/CU.
// Stage s (1..5) computes a (24-2(s-1))^2 tile at base (oy-(5-s), ox-(5-s)).
// ---------------------------------------------------------------------------
__global__ void k_jacobi5(const float* __restrict__ xin,
                          const float* __restrict__ a,
                          const float* __restrict__ f,
                          const float* __restrict__ dinv,
                          float* __restrict__ out) {
    __shared__ float sx[26][26];
    __shared__ float sa[25][26];
    __shared__ float sf[24][24];
    __shared__ float sd[24][24];
    __shared__ float sp[2][24][26];
    const float c23 = 2.0f / 3.0f, c16 = 1.0f / 6.0f, c13 = 1.0f / 3.0f;
    int b = blockIdx.z;
    const float* xb = xin + (long long)b * N2G;
    const float* ab = a + (long long)b * NCELL * NCELL;
    const float* fb = f + (long long)b * N2G;
    const float* db = dinv + (long long)b * NI2;
    int ox = blockIdx.x * 16, oy = blockIdx.y * 16;
    int tx = threadIdx.x, ty = threadIdx.y;
    int tid = ty * 16 + tx;

    for (int idx = tid; idx < 26 * 26; idx += 256) {
        int ly = idx / 26, lx = idx % 26;
        int gy = oy - 5 + ly, gx = ox - 5 + lx;
        bool in = (gy >= 0 && gy < NGRID && gx >= 0 && gx < NGRID);
        sx[ly][lx] = in ? xb[(long long)gy * NGRID + gx] : 0.0f;
    }
    for (int idx = tid; idx < 25 * 25; idx += 256) {
        int ly = idx / 25, lx = idx % 25;
        int gy = oy - 5 + ly, gx = ox - 5 + lx;
        bool in = (gy >= 0 && gy < NCELL && gx >= 0 && gx < NCELL);
        sa[ly][lx] = in ? ab[(long long)gy * NCELL + gx] : 0.0f;
    }
    for (int idx = tid; idx < 24 * 24; idx += 256) {
        int ly = idx / 24, lx = idx % 24;
        int gy = oy - 4 + ly, gx = ox - 4 + lx;
        bool ing = (gy >= 0 && gy < NGRID && gx >= 0 && gx < NGRID);
        bool itr = (gy >= 1 && gy <= NINT && gx >= 1 && gx <= NINT);
        sf[ly][lx] = ing ? fb[(long long)gy * NGRID + gx] : 0.0f;
        sd[ly][lx] = itr ? db[(long long)(gy - 1) * NINT + (gx - 1)] : 0.0f;
    }
    __syncthreads();

    // stage 1: 24x24 at base (oy-4, ox-4), reads sx (base -5 -> +1 offset)
    for (int idx = tid; idx < 24 * 24; idx += 256) {
        int ly = idx / 24, lx = idx % 24;
        int gy = oy - 4 + ly, gx = ox - 4 + lx;
        float v = 0.0f;
        if (gy >= 0 && gy < NGRID && gx >= 0 && gx < NGRID) {
            float xc = sx[ly + 1][lx + 1];
            if (gy >= 1 && gy <= NINT && gx >= 1 && gx <= NINT) {
                float a00 = sa[ly][lx], a01 = sa[ly][lx + 1];
                float a10 = sa[ly + 1][lx], a11 = sa[ly + 1][lx + 1];
                float Ax = c23 * (a00 + a01 + a10 + a11) * xc
                    - c16 * ((a00 + a01) * sx[ly][lx + 1] + (a10 + a11) * sx[ly + 2][lx + 1]
                           + (a00 + a10) * sx[ly + 1][lx] + (a01 + a11) * sx[ly + 1][lx + 2])
                    - c13 * (a00 * sx[ly][lx] + a01 * sx[ly][lx + 2]
                           + a10 * sx[ly + 2][lx] + a11 * sx[ly + 2][lx + 2]);
                v = xc + 0.75f * sd[ly][lx] * (sf[ly][lx] - Ax);
            } else {
                v = xc;
            }
        }
        sp[0][ly][lx] = v;
    }
    __syncthreads();

    // stages 2..4
    #pragma unroll 1
    for (int s = 2; s <= 4; ++s) {
        int sz = 24 - 2 * (s - 1);
        int cur = (s - 1) & 1, prv = s & 1;
        for (int idx = tid; idx < sz * sz; idx += 256) {
            int ly = idx / sz, lx = idx % sz;
            int gy = oy - (5 - s) + ly, gx = ox - (5 - s) + lx;
            float v = 0.0f;
            if (gy >= 0 && gy < NGRID && gx >= 0 && gx < NGRID) {
                float xc = sp[prv][ly + 1][lx + 1];
                if (gy >= 1 && gy <= NINT && gx >= 1 && gx <= NINT) {
                    int ar = ly + s - 1, ac = lx + s - 1;
                    float a00 = sa[ar][ac], a01 = sa[ar][ac + 1];
                    float a10 = sa[ar + 1][ac], a11 = sa[ar + 1][ac + 1];
                    float Ax = c23 * (a00 + a01 + a10 + a11) * xc
                        - c16 * ((a00 + a01) * sp[prv][ly][lx + 1] + (a10 + a11) * sp[prv][ly + 2][lx + 1]
                               + (a00 + a10) * sp[prv][ly + 1][lx] + (a01 + a11) * sp[prv][ly + 1][lx + 2])
                        - c13 * (a00 * sp[prv][ly][lx] + a01 * sp[prv][ly][lx + 2]
                               + a10 * sp[prv][ly + 2][lx] + a11 * sp[prv][ly + 2][lx + 2]);
                    int fr = ly + s - 1, fc = lx + s - 1;
                    v = xc + 0.75f * sd[fr][fc] * (sf[fr][fc] - Ax);
                } else {
                    v = xc;
                }
            }
            sp[cur][ly][lx] = v;
        }
        __syncthreads();
    }

    // stage 5: 16x16 output, one pixel/thread; prev = sp[1] (stage 4)
    {
        int gy = oy + ty, gx = ox + tx;
        if (gy < NGRID && gx < NGRID) {
            float v;
            float xc = sp[1][ty + 1][tx + 1];
            if (gy >= 1 && gy <= NINT && gx >= 1 && gx <= NINT) {
                int ar = ty + 4, ac = tx + 4;
                float a00 = sa[ar][ac], a01 = sa[ar][ac + 1];
                float a10 = sa[ar + 1][ac], a11 = sa[ar + 1][ac + 1];
                float Ax = c23 * (a00 + a01 + a10 + a11) * xc
                    - c16 * ((a00 + a01) * sp[1][ty][tx + 1] + (a10 + a11) * sp[1][ty + 2][tx + 1]
                           + (a00 + a10) * sp[1][ty + 1][tx] + (a01 + a11) * sp[1][ty + 1][tx + 2])
                    - c13 * (a00 * sp[1][ty][tx] + a01 * sp[1][ty][tx + 2]
                           + a10 * sp[1][ty + 2][tx] + a11 * sp[1][ty + 2][tx + 2]);
                v = xc + 0.75f * sd[ty + 4][tx + 4] * (sf[ty + 4][tx + 4] - Ax);
            } else {
                v = xc;
            }
            out[(long long)b * N2G + (long long)gy * NGRID + gx] = v;
        }
    }
}

__global__ void k_dinv(const float* __restrict__ a, float* __restrict__ dinv) {
    long long idx = (long long)blockIdx.x * blockDim.x + threadIdx.x;
    if (idx >= (long long)NB * NI2) return;
    int b = (int)(idx / NI2);
    int rem = (int)(idx % NI2);
    int p = rem / NINT, q = rem % NINT;
    const float* ab = a + (long long)b * NCELL * NCELL;
    float s = ab[p * NCELL + q] + ab[p * NCELL + q + 1]
            + ab[(p + 1) * NCELL + q] + ab[(p + 1) * NCELL + q + 1];
    dinv[idx] = 1.0f / ((2.0f / 3.0f) * s);
}

// ---------------------------------------------------------------------------
// Static bf16 matrix generation (hi/lo planes, K-padded, integer arg reduce)
// ---------------------------------------------------------------------------
__device__ __forceinline__ void wsplit(double v, ushort* Dh, ushort* Dl, int idx) {
    float vf = (float)v;
    ushort h = f2bf(vf);
    Dh[idx] = h;
    Dl[idx] = f2bf(vf - bf2f(h));
}

__global__ void k_genDSTA(ushort* __restrict__ Dh, ushort* __restrict__ Dl) {
    int idx = blockIdx.x * 256 + threadIdx.x;
    if (idx >= 513 * 512) return;
    int u = idx / 512, k = idx % 512;
    double v = 0.0;
    if (k < 511) {
        int t = ((u - 256) * (k + 1)) % 1024;
        if (t < 0) t += 1024;
        v = sin((M_PI / 512.0) * (double)t);
    }
    wsplit(v, Dh, Dl, idx);
}

__global__ void k_genDSTB(ushort* __restrict__ Dh, ushort* __restrict__ Dl) {
    int idx = blockIdx.x * 256 + threadIdx.x;
    if (idx >= 513 * 512) return;
    int v = idx / 512, k = idx % 512;
    double val = 0.0;
    if (k < 511) {
        int t = ((v - 256) * (k + 1)) % 1024;
        if (t < 0) t += 1024;
        val = sin((M_PI / 512.0) * (double)t) * (-1.0 / 262144.0);
    }
    wsplit(val, Dh, Dl, idx);
}

__global__ void k_genFA(ushort* __restrict__ Dh, ushort* __restrict__ Dl) {
    int idx = blockIdx.x * 256 + threadIdx.x;
    if (idx >= 511 * 1056) return;
    int y = idx / 1056, k = idx % 1056;
    double v = 0.0;
    if (k < 1026) {
        int m = (k < 513) ? k : (k - 513);
        long t = ((long)y * (m - 255)) % 1025;
        if (t < 0) t += 1025;
        double ang = (2.0 * M_PI / 1025.0) * (double)t;
        v = (k < 513) ? cos(ang) : -sin(ang);
    }
    wsplit(v, Dh, Dl, idx);
}

__global__ void k_genFB(ushort* __restrict__ Dh, ushort* __restrict__ Dl) {
    int idx = blockIdx.x * 256 + threadIdx.x;
    if (idx >= 1022 * 1056) return;
    int n = idx / 1056, k = idx % 1056;
    double v = 0.0;
    if (k < 1026) {
        int m = (k < 513) ? k : (k - 513);
        int y = (n < 511) ? n : (n - 511);
        long t = ((long)y * (m - 255)) % 1025;
        if (t < 0) t += 1025;
        double ang = (2.0 * M_PI / 1025.0) * (double)t;
        bool ktop = (k < 513), nleft = (n < 511);
        if (ktop && nleft)        v = cos(ang);
        else if (ktop && !nleft)  v = -sin(ang);
        else if (!ktop && nleft)  v = sin(ang);
        else                      v = cos(ang);
    }
    wsplit(v, Dh, Dl, idx);
}

// ---------------------------------------------------------------------------
// Dynamic fp32 -> bf16 hi/lo conversion (inputs to gemm1 / gemm3).
// ---------------------------------------------------------------------------
__global__ void k_cvtA(const float* __restrict__ s1, const float* __restrict__ s2,
                       long long bs1, long long bs2, int ld1, int ld2, int S,
                       int M, int K, int Kp,
                       ushort* __restrict__ Dh, ushort* __restrict__ Dl) {
    int b = blockIdx.y;
    int idx = blockIdx.x * 256 + threadIdx.x;
    if (idx >= M * Kp) return;
    int m = idx / Kp, k = idx % Kp;
    float v = 0.0f;
    if (k < K)
        v = (k < S) ? s1[b * bs1 + (long long)m * ld1 + k]
                    : s2[b * bs2 + (long long)m * ld2 + (k - S)];
    long long o = (long long)b * M * Kp + idx;
    ushort h = f2bf(v);
    Dh[o] = h;
    Dl[o] = f2bf(v - bf2f(h));
}

__global__ void k_cvtBt(const float* __restrict__ s1,
                        long long bs1, int ld1,
                        int N, int K, int Kp,
                        ushort* __restrict__ Dh, ushort* __restrict__ Dl) {
    int b = blockIdx.y;
    int idx = blockIdx.x * 256 + threadIdx.x;
    if (idx >= N * Kp) return;
    int n = idx / Kp, k = idx % Kp;
    float v = 0.0f;
    if (k < K)
        v = s1[b * bs1 + (long long)k * ld1 + n];
    long long o = (long long)b * N * Kp + idx;
    ushort h = f2bf(v);
    Dh[o] = h;
    Dl[o] = f2bf(v - bf2f(h));
}

// ---------------------------------------------------------------------------
// Fused split-K reduce + bf16 convert (GEMM->GEMM handoffs).
// ---------------------------------------------------------------------------
__global__ void k_redA(const float* __restrict__ P, int nsplit,
                       ushort* __restrict__ Dh, ushort* __restrict__ Dl) {
    int b = blockIdx.y;
    int idx = blockIdx.x * 256 + threadIdx.x;
    if (idx >= 513 * 512) return;
    int m = idx / 512, k = idx % 512;
    float v = 0.0f;
    if (k < 511) {
        long long base = (long long)m * 511 + k;
        #pragma unroll 4
        for (int s = 0; s < nsplit; ++s)
            v += P[((long long)b * nsplit + s) * NTT + base];
    }
    long long o = (long long)b * 513 * 512 + idx;
    ushort h = f2bf(v);
    Dh[o] = h;
    Dl[o] = f2bf(v - bf2f(h));
}

__global__ void k_redBt(const float* __restrict__ P, int nsplit,
                        ushort* __restrict__ Dh, ushort* __restrict__ Dl) {
    int b = blockIdx.y;
    int idx = blockIdx.x * 256 + threadIdx.x;
    if (idx >= 511 * 1056) return;
    int n = idx / 1056, k = idx % 1056;
    float v = 0.0f;
    if (k < 1026) {
        int row = (k < 513) ? n : (511 + n);
        int col = (k < 513) ? k : (k - 513);
        long long base = (long long)row * 513 + col;
        float acc = 0.0f;
        #pragma unroll 4
        for (int s = 0; s < nsplit; ++s)
            acc += P[((long long)b * nsplit + s) * (1022LL * 513) + base];
        v = (k < 513) ? acc : -acc;
    }
    long long o = (long long)b * 511 * 1056 + idx;
    ushort h = f2bf(v);
    Dh[o] = h;
    Dl[o] = f2bf(v - bf2f(h));
}

// ---------------------------------------------------------------------------
// MFMA real GEMM, 3-term split-bf16 (hh + hl + lh), 16x16x32 bf16 MFMA.
// (unchanged from R8 — validated)
// ---------------------------------------------------------------------------
__global__ __launch_bounds__(256) void k_mgemm(
    const ushort* __restrict__ Ah, const ushort* __restrict__ Al, long long bsA,
    const ushort* __restrict__ Bh, const ushort* __restrict__ Bl, long long bsB,
    float* __restrict__ C, long long bsC,
    int M, int N, int Kp, int nsplit) {
    __shared__ ushort sAh[128 * 40];
    __shared__ ushort sAl[128 * 40];
    __shared__ ushort sBh[128 * 40];
    __shared__ ushort sBl[128 * 40];

    int bz = blockIdx.z, b = bz / nsplit, ks = bz % nsplit;
    int kchunk = (((Kp + nsplit - 1) / nsplit) + 31) & ~31;
    int kbeg = ks * kchunk;
    int kend = min(Kp, kbeg + kchunk);

    Ah += b * bsA; Al += b * bsA;
    Bh += b * bsB; Bl += b * bsB;
    C += ((long long)b * nsplit + ks) * bsC;

    int bm = blockIdx.y * 128, bn = blockIdx.x * 128;
    int tid = threadIdx.x;
    int wave = tid >> 6, lane = tid & 63;
    int wm = (wave >> 1) * 64, wn = (wave & 1) * 64;
    int quad = lane >> 4, l16 = lane & 15;

    f32x4 zf = {0.f, 0.f, 0.f, 0.f};
    f32x4 acc[4][4];
    #pragma unroll
    for (int i = 0; i < 4; ++i)
        #pragma unroll
        for (int j = 0; j < 4; ++j) acc[i][j] = zf;

    int srow = tid >> 2;
    int sk8 = (tid & 3) * 8;

    for (int kt = kbeg; kt < kend; kt += 32) {
        #pragma unroll
        for (int h = 0; h < 2; ++h) {
            int row = srow + 64 * h;
            ushort8 vh = {0, 0, 0, 0, 0, 0, 0, 0};
            ushort8 vl = {0, 0, 0, 0, 0, 0, 0, 0};
            int gm = bm + row;
            if (gm < M) {
                vh = *(const ushort8*)(Ah + (long long)gm * Kp + kt + sk8);
                vl = *(const ushort8*)(Al + (long long)gm * Kp + kt + sk8);
            }
            *(ushort8*)(sAh + row * 40 + sk8) = vh;
            *(ushort8*)(sAl + row * 40 + sk8) = vl;
            ushort8 wh = {0, 0, 0, 0, 0, 0, 0, 0};
            ushort8 wl = {0, 0, 0, 0, 0, 0, 0, 0};
            int gn = bn + row;
            if (gn < N) {
                wh = *(const ushort8*)(Bh + (long long)gn * Kp + kt + sk8);
                wl = *(const ushort8*)(Bl + (long long)gn * Kp + kt + sk8);
            }
            *(ushort8*)(sBh + row * 40 + sk8) = wh;
            *(ushort8*)(sBl + row * 40 + sk8) = wl;
        }
        __syncthreads();

        short8 afh[4], afl[4], bfh[4], bfl[4];
        #pragma unroll
        for (int t = 0; t < 4; ++t) {
            int ar = wm + t * 16 + l16;
            afh[t] = *(const short8*)(sAh + ar * 40 + quad * 8);
            afl[t] = *(const short8*)(sAl + ar * 40 + quad * 8);
            int br = wn + t * 16 + l16;
            bfh[t] = *(const short8*)(sBh + br * 40 + quad * 8);
            bfl[t] = *(const short8*)(sBl + br * 40 + quad * 8);
        }
        #pragma unroll
        for (int mt = 0; mt < 4; ++mt)
            #pragma unroll
            for (int nt = 0; nt < 4; ++nt) {
                acc[mt][nt] = __builtin_amdgcn_mfma_f32_16x16x32_bf16(
                    afh[mt], bfh[nt], acc[mt][nt], 0, 0, 0);
                acc[mt][nt] = __builtin_amdgcn_mfma_f32_16x16x32_bf16(
                    afh[mt], bfl[nt], acc[mt][nt], 0, 0, 0);
                acc[mt][nt] = __builtin_amdgcn_mfma_f32_16x16x32_bf16(
                    afl[mt], bfh[nt], acc[mt][nt], 0, 0, 0);
            }
        __syncthreads();
    }

    #pragma unroll
    for (int mt = 0; mt < 4; ++mt) {
        #pragma unroll
        for (int r = 0; r < 4; ++r) {
            int gm = bm + wm + mt * 16 + quad * 4 + r;
            if (gm >= M) continue;
            long long rowoff = (long long)gm * N;
            #pragma unroll
            for (int nt = 0; nt < 4; ++nt) {
                int gn = bn + wn + nt * 16 + l16;
                if (gn < N) C[rowoff + gn] = acc[mt][nt][r];
            }
        }
    }
}

// ---------------------------------------------------------------------------
// Sum nsplit dense [M x N] partials -> strided fp32 output (row stride ldo).
// ---------------------------------------------------------------------------
__global__ void k_reduce(const float* __restrict__ Pr,
                         float* __restrict__ outR,
                         int MN, int N, int ldo, long long bsOut, int nsplit) {
    int b = blockIdx.y;
    for (int idx = blockIdx.x * 256 + threadIdx.x; idx < MN;
         idx += gridDim.x * 256) {
        float sr = 0.0f;
        #pragma unroll 4
        for (int s = 0; s < nsplit; ++s)
            sr += Pr[((long long)b * nsplit + s) * MN + idx];
        int m = idx / N, n = idx - m * N;
        outR[(long long)b * bsOut + (long long)m * ldo + n] = sr;
    }
}

// ---------------------------------------------------------------------------
// Complex multi-channel 3x3 conv (R16 validated: R13 compute core + packed
// bf16 intermediates via BFIN/BFOUT; halved conv traffic, 41.5 us 4->4).
// ---------------------------------------------------------------------------
template <int CIN, int COUT, bool INC, bool BFIN, bool BFOUT>
__global__ __launch_bounds__(256) void k_mcc(
    const float* __restrict__ xr, const float* __restrict__ xi,
    const float* __restrict__ wr, const float* __restrict__ wi,
    float* __restrict__ yr, float* __restrict__ yi,
    int wb, int ws1, int ws2, int conjt) {
    __shared__ float2 tile[CIN][34][18];
    __shared__ float2 wl[COUT * CIN * 9];
    int b = blockIdx.z;
    int tid = threadIdx.y * 16 + threadIdx.x;

    for (int idx = tid; idx < COUT * CIN * 9; idx += 256) {
        int co = idx / (CIN * 9);
        int r2 = idx % (CIN * 9);
        int ci = r2 / 9, s = r2 % 9;
        int p = s / 3, q = s % 3;
        int widx = conjt ? (b * wb + ci * ws1 + co * ws2 + q * 3 + p)
                         : (b * wb + co * ws1 + ci * ws2 + p * 3 + q);
        float iv = wi[widx];
        wl[idx] = make_float2(wr[widx], conjt ? -iv : iv);
    }
    int ox = blockIdx.x * 16, oy = blockIdx.y * 32;
    for (int idx = tid; idx < CIN * 34 * 18; idx += 256) {
        int ci = idx / (34 * 18), r2 = idx % (34 * 18);
        int ly = r2 / 18, lx = r2 % 18;
        int gy = oy + ly - 1, gx = ox + lx - 1;
        bool in = (gy >= 0 && gy < NGRID && gx >= 0 && gx < NGRID);
        long long gi = (long long)(b * CIN + ci) * N2G + (long long)gy * NGRID + gx;
        float vr, vi;
        if (BFIN) {
            const uint32* xp = (const uint32*)xr;
            uint32 v = in ? xp[gi] : 0u;
            vr = __uint_as_float(v << 16);
            vi = __uint_as_float(v & 0xffff0000u);
        } else {
            vr = in ? xr[gi] : 0.0f;
            vi = (INC && in) ? xi[gi] : 0.0f;
        }
        tile[ci][ly][lx] = make_float2(vr, vi);
    }
    __syncthreads();

    int tx = threadIdx.x, ty = threadIdx.y;
    float accr[2][COUT], acci[2][COUT];
    #pragma unroll
    for (int h = 0; h < 2; ++h)
        #pragma unroll
        for (int co = 0; co < COUT; ++co) { accr[h][co] = 0.0f; acci[h][co] = 0.0f; }

    #pragma unroll 1
    for (int ci = 0; ci < CIN; ++ci) {
        #pragma unroll 1
        for (int p = 0; p < 3; ++p) {
            #pragma unroll
            for (int q = 0; q < 3; ++q) {
                float2 x0 = tile[ci][ty + p][tx + q];
                float2 x1 = tile[ci][ty + 16 + p][tx + q];
                #pragma unroll
                for (int co = 0; co < COUT; ++co) {
                    float2 w = wl[(co * CIN + ci) * 9 + p * 3 + q];
                    accr[0][co] += w.x * x0.x - w.y * x0.y;
                    acci[0][co] += w.x * x0.y + w.y * x0.x;
                    accr[1][co] += w.x * x1.x - w.y * x1.y;
                    acci[1][co] += w.x * x1.y + w.y * x1.x;
                }
            }
        }
    }

    int gx = ox + tx;
    if (gx < NGRID) {
        #pragma unroll
        for (int h = 0; h < 2; ++h) {
            int gy = oy + ty + 16 * h;
            if (gy >= NGRID) continue;
            #pragma unroll
            for (int co = 0; co < COUT; ++co) {
                long long gi = (long long)(b * COUT + co) * N2G
                             + (long long)gy * NGRID + gx;
                if (BFOUT) {
                    uint32* yp = (uint32*)yr;
                    uint32 v = ((uint32)f2bf(acci[h][co]) << 16)
                             | (uint32)f2bf(accr[h][co]);
                    yp[gi] = v;
                } else {
                    yr[gi] = accr[h][co];
                    yi[gi] = acci[h][co];
                }
            }
        }
    }
}

// o *= wt * ik2  (complex multiply by wt, scale by ik2)
__global__ void k_scale(float* __restrict__ or_, float* __restrict__ oi_,
                        const float* __restrict__ wtr, const float* __restrict__ wti) {
    long long idx = (long long)blockIdx.x * blockDim.x + threadIdx.x;
    if (idx >= (long long)NB * N2G) return;
    int pix = (int)(idx % N2G);
    int u = pix / NGRID, v = pix % NGRID;
    int du = u - 256, dv = v - 256;
    float ik2;
    if (du == 0 && dv == 0)
        ik2 = 1.0f;
    else
        ik2 = (float)(1.0 / (9.869604401089358 * (double)(du * du + dv * dv)));
    float xr = or_[idx], xv = oi_[idx];
    float wrv = wtr[idx], wiv = wti[idx];
    or_[idx] = (xr * wrv - xv * wiv) * ik2;
    oi_[idx] = (xr * wiv + xv * wrv) * ik2;
}

// per-batch: red[2b] += sum(r*e), red[2b+1] += sum(Ae*e)
__global__ void k_dot2(const float* __restrict__ r, const float* __restrict__ e,
                       const float* __restrict__ Ae, float* __restrict__ red) {
    int b = blockIdx.y;
    const float* rb = r + (long long)b * N2G;
    const float* eb = e + (long long)b * N2G;
    const float* ab = Ae + (long long)b * N2G;
    float s1 = 0.0f, s2 = 0.0f;
    for (int i = blockIdx.x * blockDim.x + threadIdx.x; i < N2G;
         i += gridDim.x * blockDim.x) {
        float ev = eb[i];
        s1 += rb[i] * ev;
        s2 += ab[i] * ev;
    }
    #pragma unroll
    for (int o = 32; o > 0; o >>= 1) {
        s1 += __shfl_down(s1, o);
        s2 += __shfl_down(s2, o);
    }
    __shared__ float l1[4], l2[4];
    int wid = threadIdx.x >> 6;
    if ((threadIdx.x & 63) == 0) { l1[wid] = s1; l2[wid] = s2; }
    __syncthreads();
    if (threadIdx.x == 0) {
        atomicAdd(&red[2 * b], l1[0] + l1[1] + l1[2] + l1[3]);
        atomicAdd(&red[2 * b + 1], l2[0] + l2[1] + l2[2] + l2[3]);
    }
}

__global__ void k_update(float* __restrict__ x, const float* __restrict__ e,
                         const float* __restrict__ red) {
    long long idx = (long long)blockIdx.x * blockDim.x + threadIdx.x;
    if (idx >= (long long)NB * N2G) return;
    int b = (int)(idx / N2G);
    float alpha = red[2 * b] / red[2 * b + 1];
    x[idx] += alpha * e[idx];
}

__global__ void k_norm(const float* __restrict__ r, const float* __restrict__ f,
                       float* __restrict__ red) {
    float s1 = 0.0f, s2 = 0.0f;
    for (long long i = (long long)blockIdx.x * blockDim.x + threadIdx.x;
         i < (long long)NB * N2G; i += (long long)gridDim.x * blockDim.x) {
        float rv = r[i], fv = f[i];
        s1 += rv * rv;
        s2 += fv * fv;
    }
    #pragma unroll
    for (int o = 32; o > 0; o >>= 1) {
        s1 += __shfl_down(s1, o);
        s2 += __shfl_down(s2, o);
    }
    __shared__ float l1[4], l2[4];
    int wid = threadIdx.x >> 6;
    if ((threadIdx.x & 63) == 0) { l1[wid] = s1; l2[wid] = s2; }
    __syncthreads();
    if (threadIdx.x == 0) {
        atomicAdd(&red[8], l1[0] + l1[1] + l1[2] + l1[3]);
        atomicAdd(&red[9], l2[0] + l2[1] + l2[2] + l2[3]);
    }
}

__global__ void k_final(const float* __restrict__ red, float* __restrict__ out) {
    out[0] = sqrtf(red[8] / red[9]);
}

// ---------------------------------------------------------------------------
extern "C" void kernel_launch(void* const* d_in, const int* in_sizes, int n_in,
                              void* d_out, int out_size, void* d_ws, size_t ws_size,
                              hipStream_t stream) {
    (void)in_sizes; (void)n_in; (void)out_size; (void)ws_size;
    const float* f    = (const float*)d_in[0];
    const float* coef = (const float*)d_in[1];
    const float* w1r  = (const float*)d_in[3];
    const float* w1i  = (const float*)d_in[4];
    const float* w2r  = (const float*)d_in[5];
    const float* w2i  = (const float*)d_in[6];
    const float* w3r  = (const float*)d_in[7];
    const float* w3i  = (const float*)d_in[8];
    const float* wtr  = (const float*)d_in[9];
    const float* wti  = (const float*)d_in[10];
    float* out = (float*)d_out;

    float* ws = (float*)d_ws;
    size_t off = 0;
    auto alloc = [&](long long n) {
        float* p = ws + off;
        off += (size_t)((n + 3) & ~3LL);
        return p;
    };
    float* x0   = alloc((long long)NB * N2G);
    float* x1   = alloc((long long)NB * N2G);
    float* rr   = alloc((long long)NB * N2G);
    float* ee   = alloc((long long)NB * N2G);
    float* rh   = alloc((long long)NB * N2G);
    float* dinv = alloc((long long)NB * NI2);
    float* c1r  = alloc((long long)NB * 4 * N2G);
    float* c1i  = alloc((long long)NB * 4 * N2G);
    float* c2r  = alloc((long long)NB * 4 * N2G);
    float* c2i  = alloc((long long)NB * 4 * N2G);
    float* pr   = c1r;  // partial span (c1r..c2i contiguous)
    float* c1pk = c1r;  // packed bf16 conv intermediate 1 (uint per px-ch)
    float* c2pk = c2r;  // packed bf16 conv intermediate 2
    float* or_  = alloc((long long)NB * N2G);
    float* oi_  = alloc((long long)NB * N2G);
    float* red  = alloc(16);
    ushort* sGh  = (ushort*)alloc(513 * 512 / 2);
    ushort* sGl  = (ushort*)alloc(513 * 512 / 2);
    ushort* sGth = (ushort*)alloc(513 * 512 / 2);
    ushort* sGtl = (ushort*)alloc(513 * 512 / 2);
    ushort* sFAh = (ushort*)alloc(511 * 1056 / 2);
    ushort* sFAl = (ushort*)alloc(511 * 1056 / 2);
    ushort* sFBh = (ushort*)alloc(1022 * 1056 / 2);
    ushort* sFBl = (ushort*)alloc(1022 * 1056 / 2);
    ushort* dAh  = (ushort*)alloc((long long)NB * 513 * 1056 / 2);
    ushort* dAl  = (ushort*)alloc((long long)NB * 513 * 1056 / 2);
    ushort* dBh  = (ushort*)alloc((long long)NB * 511 * 1056 / 2);
    ushort* dBl  = (ushort*)alloc((long long)NB * 511 * 1056 / 2);
    float* Ae   = rh;  // rh is dead after the forward conv chain reads it

    dim3 blk2(16, 16);
    dim3 grdS(33, 33, NB);
    dim3 grdM(33, 17, NB);   // mcc: 16x32 output tile per block
    const int SP = 4;        // split-K (validated R15)

    hipMemsetAsync(x0, 0, (size_t)NB * N2G * sizeof(float), stream);
    k_dinv<<<dim3((NB * NI2 + 255) / 256), dim3(256), 0, stream>>>(coef, dinv);
    k_genDSTA<<<dim3((513 * 512 + 255) / 256), dim3(256), 0, stream>>>(sGh, sGl);
    k_genDSTB<<<dim3((513 * 512 + 255) / 256), dim3(256), 0, stream>>>(sGth, sGtl);
    k_genFA<<<dim3((511 * 1056 + 255) / 256), dim3(256), 0, stream>>>(sFAh, sFAl);
    k_genFB<<<dim3((1022 * 1056 + 255) / 256), dim3(256), 0, stream>>>(sFBh, sFBl);

    float* xa = x0;
    float* xb = x1;
    for (int step = 0; step < 2; ++step) {
        // 10 weighted-Jacobi sweeps as 2 fused 5-sweep launches
        for (int it = 0; it < 2; ++it) {
            k_jacobi5<<<grdS, blk2, 0, stream>>>(xa, coef, f, dinv, xb);
            float* t = xa; xa = xb; xb = t;
        }
        k_stencil<<<grdS, blk2, 0, stream>>>(xa, coef, f, nullptr, rr, 0);

        // ---- H_apply (all GEMMs via MFMA split-bf16) ----
        // gemm1: t2 = G(513x511) * rI(511x511); B^T from rr interior
        k_cvtBt<<<dim3((511 * 512 + 255) / 256, NB), dim3(256), 0, stream>>>(
            rr + NGRID + 1, N2G, NGRID, 511, 511, 512, dBh, dBl);
        k_mgemm<<<dim3(4, 5, NB * SP), dim3(256), 0, stream>>>(
            sGh, sGl, 0, dBh, dBl, (long long)511 * 512,
            pr, (long long)NTT, 513, 511, 512, SP);
        // fused reduce + convert -> gemm2 A planes
        k_redA<<<dim3(1026, NB), dim3(256), 0, stream>>>(pr, SP, dAh, dAl);
        // gemm2: rh = t2(513x511) * Gt(511x513)
        k_mgemm<<<dim3(5, 5, NB * SP), dim3(256), 0, stream>>>(
            dAh, dAl, (long long)513 * 512, sGth, sGtl, 0,
            pr, (long long)N2G, 513, 513, 512, SP);
        k_reduce<<<dim3(1024, NB), dim3(256), 0, stream>>>(
            pr, rh, N2G, NGRID, NGRID, (long long)N2G, SP);
        // forward convs: w1 (1->4), w2 (4->4), w3 (4->1); c1/c2 packed bf16
        k_mcc<1, 4, false, false, true><<<grdM, blk2, 0, stream>>>(
            rh, nullptr, w1r, w1i, c1pk, nullptr, 36, 9, 9, 0);
        k_mcc<4, 4, true, true, true><<<grdM, blk2, 0, stream>>>(
            c1pk, nullptr, w2r, w2i, c2pk, nullptr, 144, 36, 9, 0);
        k_mcc<4, 1, true, true, false><<<grdM, blk2, 0, stream>>>(
            c2pk, nullptr, w3r, w3i, or_, oi_, 36, 36, 9, 0);
        k_scale<<<dim3((NB * N2G + 255) / 256), dim3(256), 0, stream>>>(or_, oi_, wtr, wti);
        // adjoint convs
        k_mcc<1, 4, true, false, true><<<grdM, blk2, 0, stream>>>(
            or_, oi_, w3r, w3i, c1pk, nullptr, 36, 36, 9, 1);
        k_mcc<4, 4, true, true, true><<<grdM, blk2, 0, stream>>>(
            c1pk, nullptr, w2r, w2i, c2pk, nullptr, 144, 36, 9, 1);
        k_mcc<4, 1, true, true, false><<<grdM, blk2, 0, stream>>>(
            c2pk, nullptr, w1r, w1i, or_, oi_, 36, 9, 9, 1);
        // gemm3' (transposed): P'[n<1022][m<513] = sFB * [or|oi]^T
        k_cvtA<<<dim3((513 * 1056 + 255) / 256, NB), dim3(256), 0, stream>>>(
            or_, oi_, N2G, N2G, NGRID, NGRID, 513, 513, 1026, 1056, dAh, dAl);
        k_mgemm<<<dim3(5, 8, NB * 4), dim3(256), 0, stream>>>(
            sFBh, sFBl, 0, dAh, dAl, (long long)513 * 1056,
            pr, 1022LL * 513, 1022, 513, 1056, 4);
        // fused reduce + convert (+row-stack sign) -> gemm4 Bt planes
        k_redBt<<<dim3(2109, NB), dim3(256), 0, stream>>>(pr, 4, dBh, dBl);
        // gemm4: e = [Fr|Fi](511x1026) * [t2r;-t2i](1026x511)
        k_mgemm<<<dim3(4, 4, NB * SP), dim3(256), 0, stream>>>(
            sFAh, sFAl, 0, dBh, dBl, (long long)511 * 1056,
            pr, (long long)NI2, 511, 511, 1056, SP);
        hipMemsetAsync(ee, 0, (size_t)NB * N2G * sizeof(float), stream);
        k_reduce<<<dim3(1024, NB), dim3(256), 0, stream>>>(
            pr, ee + NGRID + 1, NI2, NINT, NGRID, (long long)N2G, SP);

        // Ae = A e ; alpha = (r.e)/(Ae.e) ; x += alpha e
        k_stencil<<<grdS, blk2, 0, stream>>>(ee, coef, nullptr, nullptr, Ae, 2);
        hipMemsetAsync(red, 0, 8 * sizeof(float), stream);
        k_dot2<<<dim3(64, NB), dim3(256), 0, stream>>>(rr, ee, Ae, red);
        k_update<<<dim3((NB * N2G + 255) / 256), dim3(256), 0, stream>>>(xa, ee, red);
    }
    k_stencil<<<grdS, blk2, 0, stream>>>(xa, coef, f, nullptr, rr, 0);
    hipMemsetAsync(red + 8, 0, 2 * sizeof(float), stream);
    k_norm<<<dim3(256), dim3(256), 0, stream>>>(rr, f, red);
    k_final<<<dim3(1), dim3(1), 0, stream>>>(red, out);
}